// Round 6
// baseline (869.194 us; speedup 1.0000x reference)
//
#include <hip/hip_runtime.h>
#include <math.h>

#define KNN 20
#define CNT_INV (1.0f / 1310720.0f)   // 1 / (B*N*K)

typedef short bf16x8 __attribute__((ext_vector_type(8)));   // 8 bf16 in 4 VGPRs
typedef float f32x4  __attribute__((ext_vector_type(4)));

__device__ __forceinline__ short f2bf(float f) {            // RNE f32->bf16
  unsigned u = __builtin_bit_cast(unsigned, f);
  u += 0x7FFFu + ((u >> 16) & 1u);
  return (short)(u >> 16);
}
__device__ __forceinline__ float lrelu(float y) { return y > 0.f ? y : 0.2f * y; }

// pack xt4[b][m] = {x, y, z, |x|^2}
__global__ __launch_bounds__(256) void xt4_kernel(const float* __restrict__ x,
                                                  float4* __restrict__ xt4) {
  const int t = blockIdx.x * 256 + threadIdx.x;   // < 65536
  const int b = t >> 12, m = t & 4095;
  const float* xb = x + (size_t)b * 12288;
  const float a = xb[m], c = xb[4096 + m], e = xb[8192 + m];
  xt4[t] = make_float4(a, c, e, a * a + c * c + e * e);
}

// ---------------------------------------------------------------------------
// KNN v4 + fused layer-1 BN stats. ONE WAVE per point (128-thread blocks = 2
// independent waves, zero __syncthreads). Key = 2*dot - sqm (rank-equal to
// neg_dist: -sqn is a per-query constant). 64 keys/lane in registers.
// Count(key >= T) via __ballot + scalar popcount (64 v_cmp / iter).
// Warm bracket [sqn-10, sqn+1e-3] (one-shot expansion for outliers).
// Margin collect -> exact f64 re-rank (full reference formula) of <=64
// candidates -> top-20 SET == np f64 top-k (downstream order-invariant).
// ---------------------------------------------------------------------------
__global__ __launch_bounds__(128) void knn_kernel(const float4* __restrict__ xt4,
                                                  int* __restrict__ idx_out,
                                                  const float* __restrict__ W1,
                                                  float* __restrict__ s1buf) {
  __shared__ int sl[2][64];
  __shared__ int sc[2];
  __shared__ int eidx[2][KNN];
  const int w = threadIdx.x >> 6, lane = threadIdx.x & 63;
  const int p = blockIdx.x * 2 + w;
  const int b = p >> 12, n = p & 4095;
  const float4* xb4 = xt4 + (size_t)b * 4096;

  const float4 cp = xb4[n];                 // same-addr broadcast
  const float cx0 = cp.x, cx1 = cp.y, cx2 = cp.z, sqn = cp.w;

  float w1r[6];
#pragma unroll
  for (int c = 0; c < 6; ++c) w1r[c] = W1[lane * 6 + c];

  float dr[64];
#pragma unroll
  for (int i = 0; i < 64; ++i) {
    const float4 qv = xb4[i * 64 + lane];
    const float dot = fmaf(cx0, qv.x, fmaf(cx1, qv.y, cx2 * qv.z));
    dr[i] = fmaf(2.0f, dot, -qv.w);         // key = 2*dot - sqm
  }

  // --- bisection with ballot counting; invariant cnt(lo) >= 20 ---
  float lo = sqn - 10.0f, hi = sqn + 1e-3f; // cnt(hi) = 0 (self d=0 is max)
  float T = lo;
  int cnt = 0;
#pragma unroll
  for (int i = 0; i < 64; ++i) cnt += (int)__popcll(__ballot(dr[i] >= T));
  if (cnt < 20) { hi = T; lo = sqn - 1e4f; cnt = 4096; T = lo; }  // rare outlier
  if (cnt > 48) {
    for (int it = 0; it < 26; ++it) {
      T = 0.5f * (lo + hi);
      int c = 0;
#pragma unroll
      for (int i = 0; i < 64; ++i) c += (int)__popcll(__ballot(dr[i] >= T));
      cnt = c;
      if (cnt < 20) hi = T;
      else if (cnt > 48) lo = T;
      else break;
    }
    if (cnt < 20) T = lo;                   // fallback: cnt(lo) >= 20
  }

  // --- margin collect (covers f32-vs-f64 ordering skew) ---
  if (lane == 0) sc[w] = 0;
  __builtin_amdgcn_wave_barrier();
  const float thr = T - 4e-3f;              // >> f32 key error (~2e-4)
#pragma unroll
  for (int i = 0; i < 64; ++i) {
    if (dr[i] >= thr) {
      const int pos = atomicAdd(&sc[w], 1);
      if (pos < 64) sl[w][pos] = i * 64 + lane;
    }
  }
  __builtin_amdgcn_wave_barrier();

  // --- exact f64 re-rank (reference op order), per-wave ---
  const int s = min(sc[w], 64);
  int myi = -1; double myd = -1.0e300;
  if (lane < s) {
    myi = sl[w][lane];
    const float4 av = xb4[myi];
    const double c0 = (double)cx0, c1 = (double)cx1, c2 = (double)cx2;
    const double a0 = (double)av.x, a1 = (double)av.y, a2 = (double)av.z;
    const double dot = c0 * a0 + c1 * a1 + c2 * a2;
    const double sqm = a0 * a0 + a1 * a1 + a2 * a2;
    const double sn  = c0 * c0 + c1 * c1 + c2 * c2;
    myd = (2.0 * dot - sn) - sqm;
  }
  int rank = 0;
  for (int j = 0; j < s; ++j) {
    const double od = __shfl(myd, j);
    const int    oi = __shfl(myi, j);
    if (od > myd || (od == myd && oi < myi)) ++rank;
  }
  if (lane < s && rank < KNN) { idx_out[p * KNN + rank] = myi; eidx[w][rank] = myi; }
  __builtin_amdgcn_wave_barrier();

  // --- fused layer-1 stats (lane = channel) ---
  float sm = 0.f, sq = 0.f;
#pragma unroll
  for (int k = 0; k < KNN; ++k) {
    const int kk = eidx[w][k];
    const float4 qv = xb4[kk];              // same-addr broadcast
    float y = w1r[0] * (qv.x - cx0) + w1r[1] * (qv.y - cx1) + w1r[2] * (qv.z - cx2) +
              w1r[3] * cx0 + w1r[4] * cx1 + w1r[5] * cx2;
    y = lrelu(y);
    sm += y; sq += y * y;
  }
  float* bk = s1buf + (size_t)(p & 255) * 128;
  atomicAdd(&bk[lane], sm);
  atomicAdd(&bk[64 + lane], sq);
}

// ---------------------------------------------------------------------------
// Stage kernel (MFMA): one wave per point, 4 waves/block, 8 points/wave.
// (unchanged from R5 — see comments there)
// ---------------------------------------------------------------------------
template <int STAGE>
__global__ __launch_bounds__(256, 2) void stage_kernel(
    const float* __restrict__ x, const int* __restrict__ nbr,
    const float* __restrict__ W1,
    const float* __restrict__ w2ft, const float* __restrict__ b2f,
    const float* __restrict__ w3ft, const float* __restrict__ b3f,
    float* __restrict__ sumO, float* __restrict__ sqO,
    float* __restrict__ mx, float* __restrict__ mn) {
  __shared__ float pts[4][96];
  __shared__ float W1T[384];
  __shared__ short abuf[4][2048];
  __shared__ float redS[256], redQ[256];

  const int tid = threadIdx.x, wave = tid >> 6, lane = tid & 63;
  const int q = lane >> 4, cc = lane & 15;

  for (int i = tid; i < 384; i += 256) W1T[i] = W1[(i & 63) * 6 + (i >> 6)];
  __syncthreads();

  float w1r[6];
#pragma unroll
  for (int c = 0; c < 6; ++c) w1r[c] = W1T[c * 64 + lane];

  bf16x8 w2f[2][4];
#pragma unroll
  for (int kt = 0; kt < 2; ++kt)
#pragma unroll
    for (int nt = 0; nt < 4; ++nt)
#pragma unroll
      for (int j = 0; j < 8; ++j)
        w2f[kt][nt][j] = f2bf(w2ft[(kt * 32 + q * 8 + j) * 64 + nt * 16 + cc]);
  float bias2v[4];
#pragma unroll
  for (int nt = 0; nt < 4; ++nt) bias2v[nt] = b2f[nt * 16 + cc];

  bf16x8 w3f[2][4];
  float bias3v[4];
  if (STAGE == 3) {
#pragma unroll
    for (int kt = 0; kt < 2; ++kt)
#pragma unroll
      for (int nt = 0; nt < 4; ++nt)
#pragma unroll
        for (int j = 0; j < 8; ++j)
          w3f[kt][nt][j] = f2bf(w3ft[(kt * 32 + q * 8 + j) * 64 + nt * 16 + cc]);
#pragma unroll
    for (int nt = 0; nt < 4; ++nt) bias3v[nt] = b3f[nt * 16 + cc];
  }

  const int kt1 = lane >> 5, q1 = (lane & 31) >> 3, j1 = lane & 7;
  short* ab = abuf[wave];
  const bf16x8* ab8 = (const bf16x8*)ab;
  float* pw = pts[wave];

  float s_s[4] = {0.f, 0.f, 0.f, 0.f}, s_q[4] = {0.f, 0.f, 0.f, 0.f};
  const int wgid = blockIdx.x * 4 + wave;

  for (int it = 0; it < 8; ++it) {
    const int p = wgid + it * 8192;
    const int b = p >> 12, n = p & 4095;
    const float* xb = x + (size_t)b * 12288;
    if (lane < KNN) {
      const int kk = nbr[p * KNN + lane];
      pw[lane * 4 + 0] = xb[kk];
      pw[lane * 4 + 1] = xb[4096 + kk];
      pw[lane * 4 + 2] = xb[8192 + kk];
    } else if (lane == KNN) {
      pw[80] = xb[n]; pw[81] = xb[4096 + n]; pw[82] = xb[8192 + n];
    }
    const float cx0 = pw[80], cx1 = pw[81], cx2 = pw[82];

#pragma unroll
    for (int k = 0; k < KNN; ++k) {
      const float4 pk = *(const float4*)&pw[k * 4];
      const float f0 = pk.x - cx0, f1 = pk.y - cx1, f2 = pk.z - cx2;
      float y = w1r[0] * f0 + w1r[1] * f1 + w1r[2] * f2 +
                w1r[3] * cx0 + w1r[4] * cx1 + w1r[5] * cx2;
      y = lrelu(y);
      ab[(((k >> 4) * 2 + kt1) * 64 + q1 * 16 + (k & 15)) * 8 + j1] = f2bf(y);
    }

    f32x4 acc2[2][4];
#pragma unroll
    for (int mt = 0; mt < 2; ++mt)
#pragma unroll
      for (int nt = 0; nt < 4; ++nt)
        acc2[mt][nt] = f32x4{bias2v[nt], bias2v[nt], bias2v[nt], bias2v[nt]};
#pragma unroll
    for (int kt = 0; kt < 2; ++kt) {
      const bf16x8 a0 = ab8[(0 * 2 + kt) * 64 + lane];
      const bf16x8 a1 = ab8[(1 * 2 + kt) * 64 + lane];
#pragma unroll
      for (int nt = 0; nt < 4; ++nt) {
        acc2[0][nt] = __builtin_amdgcn_mfma_f32_16x16x32_bf16(a0, w2f[kt][nt], acc2[0][nt], 0, 0, 0);
        acc2[1][nt] = __builtin_amdgcn_mfma_f32_16x16x32_bf16(a1, w2f[kt][nt], acc2[1][nt], 0, 0, 0);
      }
    }

    if (STAGE == 2) {
#pragma unroll
      for (int mt = 0; mt < 2; ++mt)
#pragma unroll
        for (int nt = 0; nt < 4; ++nt)
#pragma unroll
          for (int r = 0; r < 4; ++r) {
            if (mt == 1 && q != 0) continue;
            const float y = lrelu(acc2[mt][nt][r]);
            s_s[nt] += y; s_q[nt] += y * y;
          }
    } else {
#pragma unroll
      for (int mt = 0; mt < 2; ++mt)
#pragma unroll
        for (int nt = 0; nt < 4; ++nt) {
          const int kt3 = nt >> 1;
          const int q3 = (nt & 1) * 2 + (cc >> 3);
          const int j3 = cc & 7;
#pragma unroll
          for (int r = 0; r < 4; ++r) {
            if (mt == 1 && q != 0) continue;
            const float y = lrelu(acc2[mt][nt][r]);
            ab[((mt * 2 + kt3) * 64 + q3 * 16 + q * 4 + r) * 8 + j3] = f2bf(y);
          }
        }

      f32x4 acc3[2][4];
#pragma unroll
      for (int mt = 0; mt < 2; ++mt)
#pragma unroll
        for (int nt = 0; nt < 4; ++nt)
          acc3[mt][nt] = f32x4{bias3v[nt], bias3v[nt], bias3v[nt], bias3v[nt]};
#pragma unroll
      for (int kt = 0; kt < 2; ++kt) {
        const bf16x8 a0 = ab8[(0 * 2 + kt) * 64 + lane];
        const bf16x8 a1 = ab8[(1 * 2 + kt) * 64 + lane];
#pragma unroll
        for (int nt = 0; nt < 4; ++nt) {
          acc3[0][nt] = __builtin_amdgcn_mfma_f32_16x16x32_bf16(a0, w3f[kt][nt], acc3[0][nt], 0, 0, 0);
          acc3[1][nt] = __builtin_amdgcn_mfma_f32_16x16x32_bf16(a1, w3f[kt][nt], acc3[1][nt], 0, 0, 0);
        }
      }

      float vmx[4], vmn[4];
#pragma unroll
      for (int nt = 0; nt < 4; ++nt) { vmx[nt] = -INFINITY; vmn[nt] = INFINITY; }
#pragma unroll
      for (int mt = 0; mt < 2; ++mt)
#pragma unroll
        for (int nt = 0; nt < 4; ++nt)
#pragma unroll
          for (int r = 0; r < 4; ++r) {
            if (mt == 1 && q != 0) continue;
            const float y = lrelu(acc3[mt][nt][r]);
            s_s[nt] += y; s_q[nt] += y * y;
            vmx[nt] = fmaxf(vmx[nt], y); vmn[nt] = fminf(vmn[nt], y);
          }
#pragma unroll
      for (int nt = 0; nt < 4; ++nt) {
        vmx[nt] = fmaxf(vmx[nt], __shfl_xor(vmx[nt], 16));
        vmx[nt] = fmaxf(vmx[nt], __shfl_xor(vmx[nt], 32));
        vmn[nt] = fminf(vmn[nt], __shfl_xor(vmn[nt], 16));
        vmn[nt] = fminf(vmn[nt], __shfl_xor(vmn[nt], 32));
      }
      const float omx = q == 0 ? vmx[0] : q == 1 ? vmx[1] : q == 2 ? vmx[2] : vmx[3];
      const float omn = q == 0 ? vmn[0] : q == 1 ? vmn[1] : q == 2 ? vmn[2] : vmn[3];
      mx[(size_t)p * 64 + lane] = omx;
      mn[(size_t)p * 64 + lane] = omn;
    }
  }

#pragma unroll
  for (int nt = 0; nt < 4; ++nt) {
    s_s[nt] += __shfl_xor(s_s[nt], 16); s_s[nt] += __shfl_xor(s_s[nt], 32);
    s_q[nt] += __shfl_xor(s_q[nt], 16); s_q[nt] += __shfl_xor(s_q[nt], 32);
  }
  const float ms = q == 0 ? s_s[0] : q == 1 ? s_s[1] : q == 2 ? s_s[2] : s_s[3];
  const float mq = q == 0 ? s_q[0] : q == 1 ? s_q[1] : q == 2 ? s_q[2] : s_q[3];
  redS[tid] = ms; redQ[tid] = mq;
  __syncthreads();
  if (tid < 64) {
    const float s  = redS[tid] + redS[64 + tid] + redS[128 + tid] + redS[192 + tid];
    const float qq = redQ[tid] + redQ[64 + tid] + redQ[128 + tid] + redQ[192 + tid];
    atomicAdd(&sumO[tid], s);
    atomicAdd(&sqO[tid], qq);
  }
}

// fold1: sum 256 stat buckets, then fold BN into W2 (transposed + bias)
__global__ void fold1_kernel(const float* __restrict__ s1buf,
                             const float* __restrict__ g, const float* __restrict__ bt,
                             const float* __restrict__ W,
                             float* __restrict__ WfT, float* __restrict__ bf) {
  __shared__ float s[64], t[64];
  const int o = threadIdx.x;
  float sm = 0.f, qq = 0.f;
  for (int k = 0; k < 256; ++k) { sm += s1buf[k * 128 + o]; qq += s1buf[k * 128 + 64 + o]; }
  const float mu = sm * CNT_INV;
  const float var = qq * CNT_INV - mu * mu;
  const float sc = g[o] / sqrtf(var + 1e-5f);
  s[o] = sc; t[o] = bt[o] - mu * sc;
  __syncthreads();
  float acc = 0.f;
  for (int c = 0; c < 64; ++c) {
    const float w = W[o * 64 + c];
    WfT[c * 64 + o] = w * s[c];
    acc += w * t[c];
  }
  bf[o] = acc;
}

__global__ void fold_kernel(const float* __restrict__ sum, const float* __restrict__ sq,
                            const float* __restrict__ g, const float* __restrict__ bt,
                            const float* __restrict__ W,
                            float* __restrict__ WfT, float* __restrict__ bf) {
  __shared__ float s[64], t[64];
  const int o = threadIdx.x;
  const float mu = sum[o] * CNT_INV;
  const float var = sq[o] * CNT_INV - mu * mu;
  const float sc = g[o] / sqrtf(var + 1e-5f);
  s[o] = sc; t[o] = bt[o] - mu * sc;
  __syncthreads();
  float acc = 0.f;
  for (int c = 0; c < 64; ++c) {
    const float w = W[o * 64 + c];
    WfT[c * 64 + o] = w * s[c];
    acc += w * t[c];
  }
  bf[o] = acc;
}

__global__ void fold3_kernel(const float* __restrict__ sum, const float* __restrict__ sq,
                             const float* __restrict__ g, const float* __restrict__ bt,
                             float* __restrict__ s3, float* __restrict__ t3) {
  const int o = threadIdx.x;
  const float mu = sum[o] * CNT_INV;
  const float var = sq[o] * CNT_INV - mu * mu;
  const float sc = g[o] / sqrtf(var + 1e-5f);
  s3[o] = sc; t3[o] = bt[o] - mu * sc;
}

// out[b][o][n] = s3[o] * (s3>=0 ? max_k : min_k) + t3[o]
__global__ __launch_bounds__(256) void final_kernel(
    const float* __restrict__ mx, const float* __restrict__ mn,
    const float* __restrict__ s3, const float* __restrict__ t3,
    float* __restrict__ out) {
  const int t = blockIdx.x * 256 + threadIdx.x;
  const int n = t & 4095;
  const int o = (t >> 12) & 63;
  const int b = t >> 18;
  const float sc = s3[o], tt = t3[o];
  const size_t src = ((size_t)(b * 4096 + n)) * 64 + o;
  const float v = sc >= 0.f ? mx[src] : mn[src];
  out[t] = sc * v + tt;
}

extern "C" void kernel_launch(void* const* d_in, const int* in_sizes, int n_in,
                              void* d_out, int out_size, void* d_ws, size_t ws_size,
                              hipStream_t stream) {
  const float* x  = (const float*)d_in[0];
  const float* W1 = (const float*)d_in[1];
  const float* W2 = (const float*)d_in[2];
  const float* W3 = (const float*)d_in[3];
  const float* g1 = (const float*)d_in[4];
  const float* b1 = (const float*)d_in[5];
  const float* g2 = (const float*)d_in[6];
  const float* b2 = (const float*)d_in[7];
  float* out = (float*)d_out;

  char* ws = (char*)d_ws;
  float4* xt4 = (float4*)ws;                        // 16*4096*16 = 1,048,576 B
  int* idx = (int*)(ws + 1048576);                  // 5,242,880 B
  float* F = (float*)(ws + 6291456);
  float* sum2 = F + 0,   * sq2 = F + 64;
  float* sum3 = F + 128, * sq3 = F + 192;
  float* s1buf = F + 256;                           // 256 buckets x 128
  float* W2fT = F + 33024;                          // 4096
  float* b2f  = F + 37120;                          // 64
  float* W3fT = F + 37184;                          // 4096
  float* b3f  = F + 41280;                          // 64
  float* s3   = F + 41344;
  float* t3   = F + 41408;
  float* mx = (float*)(ws + 6457344);               // [B*N][64]
  float* mn = mx + (size_t)16 * 4096 * 64;

  hipMemsetAsync(F, 0, 33024 * sizeof(float), stream);   // stats + buckets

  xt4_kernel<<<256, 256, 0, stream>>>(x, xt4);
  knn_kernel<<<32768, 128, 0, stream>>>(xt4, idx, W1, s1buf);
  fold1_kernel<<<1, 64, 0, stream>>>(s1buf, g1, b1, W2, W2fT, b2f);
  stage_kernel<2><<<2048, 256, 0, stream>>>(x, idx, W1, W2fT, b2f, nullptr,
                                            nullptr, sum2, sq2, nullptr, nullptr);
  fold_kernel<<<1, 64, 0, stream>>>(sum2, sq2, g1, b1, W3, W3fT, b3f);
  stage_kernel<3><<<2048, 256, 0, stream>>>(x, idx, W1, W2fT, b2f, W3fT,
                                            b3f, sum3, sq3, mx, mn);
  fold3_kernel<<<1, 64, 0, stream>>>(sum3, sq3, g2, b2, s3, t3);
  final_kernel<<<16384, 256, 0, stream>>>(mx, mn, s3, t3, out);
}

// Round 7
// 702.721 us; speedup vs baseline: 1.2369x; 1.2369x over previous
//
#include <hip/hip_runtime.h>
#include <math.h>

#define KNN 20
#define CNT_INV (1.0f / 1310720.0f)   // 1 / (B*N*K)

typedef short bf16x8 __attribute__((ext_vector_type(8)));   // 8 bf16 in 4 VGPRs
typedef float f32x4  __attribute__((ext_vector_type(4)));

__device__ __forceinline__ short f2bf(float f) {            // RNE f32->bf16
  unsigned u = __builtin_bit_cast(unsigned, f);
  u += 0x7FFFu + ((u >> 16) & 1u);
  return (short)(u >> 16);
}
__device__ __forceinline__ float lrelu(float y) { return y > 0.f ? y : 0.2f * y; }

// pack xt4[b][m] = {x, y, z, |x|^2}
__global__ __launch_bounds__(256) void xt4_kernel(const float* __restrict__ x,
                                                  float4* __restrict__ xt4) {
  const int t = blockIdx.x * 256 + threadIdx.x;   // < 65536
  const int b = t >> 12, m = t & 4095;
  const float* xb = x + (size_t)b * 12288;
  const float a = xb[m], c = xb[4096 + m], e = xb[8192 + m];
  xt4[t] = make_float4(a, c, e, a * a + c * c + e * e);
}

// ---------------------------------------------------------------------------
// KNN v5 + fused layer-1 BN stats. Block (256 thr) per point — the R5 shell
// that measured 86% VALUBusy / 78% occupancy — with cheaper inner loops:
//  * xt4 packed loads: key = 2*dot - sqm (rank-equal: -sqn is per-query
//    constant) = 1 dwordx4 + 4 VALU per candidate.
//  * ballot counting: bisection iter = 16 v_cmp + SALU popcounts (was 44 VALU).
//  * warm bracket [sqn-10, sqn+1e-3] (~8 iters; one-shot widen for outliers).
// Margin collect -> exact f64 re-rank (reference op order) of <=64 cands ->
// top-20 SET == np f64 top-k (downstream is order-invariant).
// ---------------------------------------------------------------------------
__global__ __launch_bounds__(256) void knn_kernel(const float4* __restrict__ xt4,
                                                  int* __restrict__ idx_out,
                                                  const float* __restrict__ W1,
                                                  float* __restrict__ s1buf) {
  __shared__ int wcnt[8];          // double-buffered per-wave counts
  __shared__ int slist[64];
  __shared__ int scount;
  __shared__ int eidx[KNN];
  __shared__ float redS[256], redQ[256];
  const int p = blockIdx.x;
  const int b = p >> 12, n = p & 4095;
  const int tid = threadIdx.x, lane = tid & 63, wid = tid >> 6;
  const float4* xb4 = xt4 + (size_t)b * 4096;
  const float4 cp = xb4[n];                   // block-uniform -> scalar load
  const float cx0 = cp.x, cx1 = cp.y, cx2 = cp.z, sqn = cp.w;

  float w1r[6];
#pragma unroll
  for (int c = 0; c < 6; ++c) w1r[c] = W1[lane * 6 + c];

  float dr[16];
#pragma unroll
  for (int i = 0; i < 16; ++i) {
    const float4 qv = xb4[i * 256 + tid];
    const float dot = fmaf(cx0, qv.x, fmaf(cx1, qv.y, cx2 * qv.z));
    dr[i] = fmaf(2.0f, dot, -qv.w);           // key = 2*dot - sqm
  }

  // count(key >= T) over the block: per-wave ballots + LDS combine.
  // All control flow below is block-uniform (T/lo/hi/cnt are uniform).
  int phase = 0;
  auto bcount = [&](float T) -> int {
    int c = 0;
#pragma unroll
    for (int i = 0; i < 16; ++i) c += (int)__popcll(__ballot(dr[i] >= T));
    if (lane == 0) wcnt[(phase & 1) * 4 + wid] = c;
    __syncthreads();
    const int* wc = &wcnt[(phase & 1) * 4];
    ++phase;
    return wc[0] + wc[1] + wc[2] + wc[3];
  };

  float lo = sqn - 10.0f, hi = sqn + 1e-3f, T = lo;   // cnt(hi)=0: self key=sqn is max
  int cnt = bcount(T);
  if (cnt < 20) { lo = sqn - 1e4f; T = lo; cnt = bcount(T); }   // ~never (outlier)
  if (cnt > 48) {
    for (int it = 0; it < 24; ++it) {
      T = 0.5f * (lo + hi);
      cnt = bcount(T);
      if (cnt < 20) hi = T;
      else if (cnt > 48) lo = T;
      else break;
    }
    if (cnt < 20) T = lo;                     // fallback keeps invariant cnt>=20
  }

  if (tid == 0) scount = 0;
  __syncthreads();
  const float thr = T - 4e-3f;                // margin >> f32 key error (~2e-4)
#pragma unroll
  for (int i = 0; i < 16; ++i) {
    if (dr[i] >= thr) {
      const int pos = atomicAdd(&scount, 1);
      if (pos < 64) slist[pos] = i * 256 + tid;
    }
  }
  __syncthreads();

  if (tid < 64) {                             // wave 0: exact f64 re-rank of S
    const int s = min(scount, 64);
    int myi = -1; double myd = -1.0e300;
    if (tid < s) {
      myi = slist[tid];
      const float4 av = xb4[myi];
      const double c0 = (double)cx0, c1 = (double)cx1, c2 = (double)cx2;
      const double a0 = (double)av.x, a1 = (double)av.y, a2 = (double)av.z;
      const double dot = c0 * a0 + c1 * a1 + c2 * a2;
      const double sqm = a0 * a0 + a1 * a1 + a2 * a2;
      const double sn  = c0 * c0 + c1 * c1 + c2 * c2;
      myd = (2.0 * dot - sn) - sqm;
    }
    int rank = 0;
    for (int j = 0; j < s; ++j) {
      const double od = __shfl(myd, j);
      const int    oi = __shfl(myi, j);
      if (od > myd || (od == myd && oi < myi)) ++rank;
    }
    if (tid < s && rank < KNN) { idx_out[p * KNN + rank] = myi; eidx[rank] = myi; }
  }
  __syncthreads();

  // fused layer-1 stats: channel o = lane, k = (tid>>6) + 4t
  const int kb = tid >> 6;
  float sm = 0.f, sq = 0.f;
#pragma unroll
  for (int t = 0; t < 5; ++t) {
    const int kk = eidx[kb + 4 * t];
    const float4 qv = xb4[kk];                // same-addr broadcast in wave
    float y = w1r[0] * (qv.x - cx0) + w1r[1] * (qv.y - cx1) + w1r[2] * (qv.z - cx2) +
              w1r[3] * cx0 + w1r[4] * cx1 + w1r[5] * cx2;
    y = lrelu(y);
    sm += y; sq += y * y;
  }
  redS[tid] = sm; redQ[tid] = sq;
  __syncthreads();
  if (tid < 64) {
    const float s  = redS[tid] + redS[64 + tid] + redS[128 + tid] + redS[192 + tid];
    const float qq = redQ[tid] + redQ[64 + tid] + redQ[128 + tid] + redQ[192 + tid];
    float* bk = s1buf + (size_t)(p & 255) * 128;
    atomicAdd(&bk[tid], s);
    atomicAdd(&bk[64 + tid], qq);
  }
}

// ---------------------------------------------------------------------------
// Stage kernel (MFMA): one wave per point, 4 waves/block, 8 points/wave.
// (unchanged from R5 — see comments there)
// ---------------------------------------------------------------------------
template <int STAGE>
__global__ __launch_bounds__(256, 2) void stage_kernel(
    const float* __restrict__ x, const int* __restrict__ nbr,
    const float* __restrict__ W1,
    const float* __restrict__ w2ft, const float* __restrict__ b2f,
    const float* __restrict__ w3ft, const float* __restrict__ b3f,
    float* __restrict__ sumO, float* __restrict__ sqO,
    float* __restrict__ mx, float* __restrict__ mn) {
  __shared__ float pts[4][96];
  __shared__ float W1T[384];
  __shared__ short abuf[4][2048];
  __shared__ float redS[256], redQ[256];

  const int tid = threadIdx.x, wave = tid >> 6, lane = tid & 63;
  const int q = lane >> 4, cc = lane & 15;

  for (int i = tid; i < 384; i += 256) W1T[i] = W1[(i & 63) * 6 + (i >> 6)];
  __syncthreads();

  float w1r[6];
#pragma unroll
  for (int c = 0; c < 6; ++c) w1r[c] = W1T[c * 64 + lane];

  bf16x8 w2f[2][4];
#pragma unroll
  for (int kt = 0; kt < 2; ++kt)
#pragma unroll
    for (int nt = 0; nt < 4; ++nt)
#pragma unroll
      for (int j = 0; j < 8; ++j)
        w2f[kt][nt][j] = f2bf(w2ft[(kt * 32 + q * 8 + j) * 64 + nt * 16 + cc]);
  float bias2v[4];
#pragma unroll
  for (int nt = 0; nt < 4; ++nt) bias2v[nt] = b2f[nt * 16 + cc];

  bf16x8 w3f[2][4];
  float bias3v[4];
  if (STAGE == 3) {
#pragma unroll
    for (int kt = 0; kt < 2; ++kt)
#pragma unroll
      for (int nt = 0; nt < 4; ++nt)
#pragma unroll
        for (int j = 0; j < 8; ++j)
          w3f[kt][nt][j] = f2bf(w3ft[(kt * 32 + q * 8 + j) * 64 + nt * 16 + cc]);
#pragma unroll
    for (int nt = 0; nt < 4; ++nt) bias3v[nt] = b3f[nt * 16 + cc];
  }

  const int kt1 = lane >> 5, q1 = (lane & 31) >> 3, j1 = lane & 7;
  short* ab = abuf[wave];
  const bf16x8* ab8 = (const bf16x8*)ab;
  float* pw = pts[wave];

  float s_s[4] = {0.f, 0.f, 0.f, 0.f}, s_q[4] = {0.f, 0.f, 0.f, 0.f};
  const int wgid = blockIdx.x * 4 + wave;

  for (int it = 0; it < 8; ++it) {
    const int p = wgid + it * 8192;
    const int b = p >> 12, n = p & 4095;
    const float* xb = x + (size_t)b * 12288;
    if (lane < KNN) {
      const int kk = nbr[p * KNN + lane];
      pw[lane * 4 + 0] = xb[kk];
      pw[lane * 4 + 1] = xb[4096 + kk];
      pw[lane * 4 + 2] = xb[8192 + kk];
    } else if (lane == KNN) {
      pw[80] = xb[n]; pw[81] = xb[4096 + n]; pw[82] = xb[8192 + n];
    }
    const float cx0 = pw[80], cx1 = pw[81], cx2 = pw[82];

#pragma unroll
    for (int k = 0; k < KNN; ++k) {
      const float4 pk = *(const float4*)&pw[k * 4];
      const float f0 = pk.x - cx0, f1 = pk.y - cx1, f2 = pk.z - cx2;
      float y = w1r[0] * f0 + w1r[1] * f1 + w1r[2] * f2 +
                w1r[3] * cx0 + w1r[4] * cx1 + w1r[5] * cx2;
      y = lrelu(y);
      ab[(((k >> 4) * 2 + kt1) * 64 + q1 * 16 + (k & 15)) * 8 + j1] = f2bf(y);
    }

    f32x4 acc2[2][4];
#pragma unroll
    for (int mt = 0; mt < 2; ++mt)
#pragma unroll
      for (int nt = 0; nt < 4; ++nt)
        acc2[mt][nt] = f32x4{bias2v[nt], bias2v[nt], bias2v[nt], bias2v[nt]};
#pragma unroll
    for (int kt = 0; kt < 2; ++kt) {
      const bf16x8 a0 = ab8[(0 * 2 + kt) * 64 + lane];
      const bf16x8 a1 = ab8[(1 * 2 + kt) * 64 + lane];
#pragma unroll
      for (int nt = 0; nt < 4; ++nt) {
        acc2[0][nt] = __builtin_amdgcn_mfma_f32_16x16x32_bf16(a0, w2f[kt][nt], acc2[0][nt], 0, 0, 0);
        acc2[1][nt] = __builtin_amdgcn_mfma_f32_16x16x32_bf16(a1, w2f[kt][nt], acc2[1][nt], 0, 0, 0);
      }
    }

    if (STAGE == 2) {
#pragma unroll
      for (int mt = 0; mt < 2; ++mt)
#pragma unroll
        for (int nt = 0; nt < 4; ++nt)
#pragma unroll
          for (int r = 0; r < 4; ++r) {
            if (mt == 1 && q != 0) continue;
            const float y = lrelu(acc2[mt][nt][r]);
            s_s[nt] += y; s_q[nt] += y * y;
          }
    } else {
#pragma unroll
      for (int mt = 0; mt < 2; ++mt)
#pragma unroll
        for (int nt = 0; nt < 4; ++nt) {
          const int kt3 = nt >> 1;
          const int q3 = (nt & 1) * 2 + (cc >> 3);
          const int j3 = cc & 7;
#pragma unroll
          for (int r = 0; r < 4; ++r) {
            if (mt == 1 && q != 0) continue;
            const float y = lrelu(acc2[mt][nt][r]);
            ab[((mt * 2 + kt3) * 64 + q3 * 16 + q * 4 + r) * 8 + j3] = f2bf(y);
          }
        }

      f32x4 acc3[2][4];
#pragma unroll
      for (int mt = 0; mt < 2; ++mt)
#pragma unroll
        for (int nt = 0; nt < 4; ++nt)
          acc3[mt][nt] = f32x4{bias3v[nt], bias3v[nt], bias3v[nt], bias3v[nt]};
#pragma unroll
      for (int kt = 0; kt < 2; ++kt) {
        const bf16x8 a0 = ab8[(0 * 2 + kt) * 64 + lane];
        const bf16x8 a1 = ab8[(1 * 2 + kt) * 64 + lane];
#pragma unroll
        for (int nt = 0; nt < 4; ++nt) {
          acc3[0][nt] = __builtin_amdgcn_mfma_f32_16x16x32_bf16(a0, w3f[kt][nt], acc3[0][nt], 0, 0, 0);
          acc3[1][nt] = __builtin_amdgcn_mfma_f32_16x16x32_bf16(a1, w3f[kt][nt], acc3[1][nt], 0, 0, 0);
        }
      }

      float vmx[4], vmn[4];
#pragma unroll
      for (int nt = 0; nt < 4; ++nt) { vmx[nt] = -INFINITY; vmn[nt] = INFINITY; }
#pragma unroll
      for (int mt = 0; mt < 2; ++mt)
#pragma unroll
        for (int nt = 0; nt < 4; ++nt)
#pragma unroll
          for (int r = 0; r < 4; ++r) {
            if (mt == 1 && q != 0) continue;
            const float y = lrelu(acc3[mt][nt][r]);
            s_s[nt] += y; s_q[nt] += y * y;
            vmx[nt] = fmaxf(vmx[nt], y); vmn[nt] = fminf(vmn[nt], y);
          }
#pragma unroll
      for (int nt = 0; nt < 4; ++nt) {
        vmx[nt] = fmaxf(vmx[nt], __shfl_xor(vmx[nt], 16));
        vmx[nt] = fmaxf(vmx[nt], __shfl_xor(vmx[nt], 32));
        vmn[nt] = fminf(vmn[nt], __shfl_xor(vmn[nt], 16));
        vmn[nt] = fminf(vmn[nt], __shfl_xor(vmn[nt], 32));
      }
      const float omx = q == 0 ? vmx[0] : q == 1 ? vmx[1] : q == 2 ? vmx[2] : vmx[3];
      const float omn = q == 0 ? vmn[0] : q == 1 ? vmn[1] : q == 2 ? vmn[2] : vmn[3];
      mx[(size_t)p * 64 + lane] = omx;
      mn[(size_t)p * 64 + lane] = omn;
    }
  }

#pragma unroll
  for (int nt = 0; nt < 4; ++nt) {
    s_s[nt] += __shfl_xor(s_s[nt], 16); s_s[nt] += __shfl_xor(s_s[nt], 32);
    s_q[nt] += __shfl_xor(s_q[nt], 16); s_q[nt] += __shfl_xor(s_q[nt], 32);
  }
  const float ms = q == 0 ? s_s[0] : q == 1 ? s_s[1] : q == 2 ? s_s[2] : s_s[3];
  const float mq = q == 0 ? s_q[0] : q == 1 ? s_q[1] : q == 2 ? s_q[2] : s_q[3];
  redS[tid] = ms; redQ[tid] = mq;
  __syncthreads();
  if (tid < 64) {
    const float s  = redS[tid] + redS[64 + tid] + redS[128 + tid] + redS[192 + tid];
    const float qq = redQ[tid] + redQ[64 + tid] + redQ[128 + tid] + redQ[192 + tid];
    atomicAdd(&sumO[tid], s);
    atomicAdd(&sqO[tid], qq);
  }
}

// fold1: sum 256 stat buckets, then fold BN into W2 (transposed + bias)
__global__ void fold1_kernel(const float* __restrict__ s1buf,
                             const float* __restrict__ g, const float* __restrict__ bt,
                             const float* __restrict__ W,
                             float* __restrict__ WfT, float* __restrict__ bf) {
  __shared__ float s[64], t[64];
  const int o = threadIdx.x;
  float sm = 0.f, qq = 0.f;
  for (int k = 0; k < 256; ++k) { sm += s1buf[k * 128 + o]; qq += s1buf[k * 128 + 64 + o]; }
  const float mu = sm * CNT_INV;
  const float var = qq * CNT_INV - mu * mu;
  const float sc = g[o] / sqrtf(var + 1e-5f);
  s[o] = sc; t[o] = bt[o] - mu * sc;
  __syncthreads();
  float acc = 0.f;
  for (int c = 0; c < 64; ++c) {
    const float w = W[o * 64 + c];
    WfT[c * 64 + o] = w * s[c];
    acc += w * t[c];
  }
  bf[o] = acc;
}

__global__ void fold_kernel(const float* __restrict__ sum, const float* __restrict__ sq,
                            const float* __restrict__ g, const float* __restrict__ bt,
                            const float* __restrict__ W,
                            float* __restrict__ WfT, float* __restrict__ bf) {
  __shared__ float s[64], t[64];
  const int o = threadIdx.x;
  const float mu = sum[o] * CNT_INV;
  const float var = sq[o] * CNT_INV - mu * mu;
  const float sc = g[o] / sqrtf(var + 1e-5f);
  s[o] = sc; t[o] = bt[o] - mu * sc;
  __syncthreads();
  float acc = 0.f;
  for (int c = 0; c < 64; ++c) {
    const float w = W[o * 64 + c];
    WfT[c * 64 + o] = w * s[c];
    acc += w * t[c];
  }
  bf[o] = acc;
}

__global__ void fold3_kernel(const float* __restrict__ sum, const float* __restrict__ sq,
                             const float* __restrict__ g, const float* __restrict__ bt,
                             float* __restrict__ s3, float* __restrict__ t3) {
  const int o = threadIdx.x;
  const float mu = sum[o] * CNT_INV;
  const float var = sq[o] * CNT_INV - mu * mu;
  const float sc = g[o] / sqrtf(var + 1e-5f);
  s3[o] = sc; t3[o] = bt[o] - mu * sc;
}

// out[b][o][n] = s3[o] * (s3>=0 ? max_k : min_k) + t3[o]
__global__ __launch_bounds__(256) void final_kernel(
    const float* __restrict__ mx, const float* __restrict__ mn,
    const float* __restrict__ s3, const float* __restrict__ t3,
    float* __restrict__ out) {
  const int t = blockIdx.x * 256 + threadIdx.x;
  const int n = t & 4095;
  const int o = (t >> 12) & 63;
  const int b = t >> 18;
  const float sc = s3[o], tt = t3[o];
  const size_t src = ((size_t)(b * 4096 + n)) * 64 + o;
  const float v = sc >= 0.f ? mx[src] : mn[src];
  out[t] = sc * v + tt;
}

extern "C" void kernel_launch(void* const* d_in, const int* in_sizes, int n_in,
                              void* d_out, int out_size, void* d_ws, size_t ws_size,
                              hipStream_t stream) {
  const float* x  = (const float*)d_in[0];
  const float* W1 = (const float*)d_in[1];
  const float* W2 = (const float*)d_in[2];
  const float* W3 = (const float*)d_in[3];
  const float* g1 = (const float*)d_in[4];
  const float* b1 = (const float*)d_in[5];
  const float* g2 = (const float*)d_in[6];
  const float* b2 = (const float*)d_in[7];
  float* out = (float*)d_out;

  char* ws = (char*)d_ws;
  float4* xt4 = (float4*)ws;                        // 16*4096*16 = 1,048,576 B
  int* idx = (int*)(ws + 1048576);                  // 5,242,880 B
  float* F = (float*)(ws + 6291456);
  float* sum2 = F + 0,   * sq2 = F + 64;
  float* sum3 = F + 128, * sq3 = F + 192;
  float* s1buf = F + 256;                           // 256 buckets x 128
  float* W2fT = F + 33024;                          // 4096
  float* b2f  = F + 37120;                          // 64
  float* W3fT = F + 37184;                          // 4096
  float* b3f  = F + 41280;                          // 64
  float* s3   = F + 41344;
  float* t3   = F + 41408;
  float* mx = (float*)(ws + 6457344);               // [B*N][64]
  float* mn = mx + (size_t)16 * 4096 * 64;

  hipMemsetAsync(F, 0, 33024 * sizeof(float), stream);   // stats + buckets

  xt4_kernel<<<256, 256, 0, stream>>>(x, xt4);
  knn_kernel<<<65536, 256, 0, stream>>>(xt4, idx, W1, s1buf);
  fold1_kernel<<<1, 64, 0, stream>>>(s1buf, g1, b1, W2, W2fT, b2f);
  stage_kernel<2><<<2048, 256, 0, stream>>>(x, idx, W1, W2fT, b2f, nullptr,
                                            nullptr, sum2, sq2, nullptr, nullptr);
  fold_kernel<<<1, 64, 0, stream>>>(sum2, sq2, g1, b1, W3, W3fT, b3f);
  stage_kernel<3><<<2048, 256, 0, stream>>>(x, idx, W1, W2fT, b2f, W3fT,
                                            b3f, sum3, sq3, mx, mn);
  fold3_kernel<<<1, 64, 0, stream>>>(sum3, sq3, g2, b2, s3, t3);
  final_kernel<<<16384, 256, 0, stream>>>(mx, mn, s3, t3, out);
}

// Round 9
// 694.399 us; speedup vs baseline: 1.2517x; 1.0120x over previous
//
#include <hip/hip_runtime.h>
#include <math.h>

#define KNN 20
#define CNT_INV (1.0f / 1310720.0f)   // 1 / (B*N*K)

typedef short bf16x8 __attribute__((ext_vector_type(8)));   // 8 bf16 in 4 VGPRs
typedef float f32x4  __attribute__((ext_vector_type(4)));

__device__ __forceinline__ short f2bf(float f) {            // RNE f32->bf16
  unsigned u = __builtin_bit_cast(unsigned, f);
  u += 0x7FFFu + ((u >> 16) & 1u);
  return (short)(u >> 16);
}
__device__ __forceinline__ float lrelu(float y) { return y > 0.f ? y : 0.2f * y; }

// pack xt4[b][m] = {x, y, z, |x|^2}
__global__ __launch_bounds__(256) void xt4_kernel(const float* __restrict__ x,
                                                  float4* __restrict__ xt4) {
  const int t = blockIdx.x * 256 + threadIdx.x;   // < 65536
  const int b = t >> 12, m = t & 4095;
  const float* xb = x + (size_t)b * 12288;
  const float a = xb[m], c = xb[4096 + m], e = xb[8192 + m];
  xt4[t] = make_float4(a, c, e, a * a + c * c + e * e);
}

// ---------------------------------------------------------------------------
// KNN v5 (R7-verified) + fused layer-1 BN stats. Block (256 thr) per point.
//  * xt4 packed loads: key = 2*dot - sqm (rank-equal: -sqn is per-query const)
//  * ballot counting bisection on count(key>=T); warm bracket [sqn-10, sqn]
//  * margin collect -> exact f64 re-rank (reference op order) of <=64 cands
//    -> top-20 SET == np f64 top-k (downstream is order-invariant).
// ---------------------------------------------------------------------------
__global__ __launch_bounds__(256) void knn_kernel(const float4* __restrict__ xt4,
                                                  int* __restrict__ idx_out,
                                                  const float* __restrict__ W1,
                                                  float* __restrict__ s1buf) {
  __shared__ int wcnt[8];          // double-buffered per-wave counts
  __shared__ int slist[64];
  __shared__ int scount;
  __shared__ int eidx[KNN];
  __shared__ float redS[256], redQ[256];
  const int p = blockIdx.x;
  const int b = p >> 12, n = p & 4095;
  const int tid = threadIdx.x, lane = tid & 63, wid = tid >> 6;
  const float4* xb4 = xt4 + (size_t)b * 4096;
  const float4 cp = xb4[n];                   // block-uniform
  const float cx0 = cp.x, cx1 = cp.y, cx2 = cp.z, sqn = cp.w;

  float w1r[6];
#pragma unroll
  for (int c = 0; c < 6; ++c) w1r[c] = W1[lane * 6 + c];

  float dr[16];
#pragma unroll
  for (int i = 0; i < 16; ++i) {
    const float4 qv = xb4[i * 256 + tid];
    const float dot = fmaf(cx0, qv.x, fmaf(cx1, qv.y, cx2 * qv.z));
    dr[i] = fmaf(2.0f, dot, -qv.w);           // key = 2*dot - sqm
  }

  // count(key >= T) over the block: per-wave ballots + LDS combine.
  // All control flow below is block-uniform (T/lo/hi/cnt are uniform).
  int phase = 0;
  auto bcount = [&](float T) -> int {
    int c = 0;
#pragma unroll
    for (int i = 0; i < 16; ++i) c += (int)__popcll(__ballot(dr[i] >= T));
    if (lane == 0) wcnt[(phase & 1) * 4 + wid] = c;
    __syncthreads();
    const int* wc = &wcnt[(phase & 1) * 4];
    ++phase;
    return wc[0] + wc[1] + wc[2] + wc[3];
  };

  float lo = sqn - 10.0f, hi = sqn + 1e-3f, T = lo;   // cnt(hi)=0: self key=sqn is max
  int cnt = bcount(T);
  if (cnt < 20) { lo = sqn - 1e4f; T = lo; cnt = bcount(T); }   // ~never (outlier)
  if (cnt > 48) {
    for (int it = 0; it < 24; ++it) {
      T = 0.5f * (lo + hi);
      cnt = bcount(T);
      if (cnt < 20) hi = T;
      else if (cnt > 48) lo = T;
      else break;
    }
    if (cnt < 20) T = lo;                     // fallback keeps invariant cnt>=20
  }

  if (tid == 0) scount = 0;
  __syncthreads();
  const float thr = T - 4e-3f;                // margin >> f32 key error (~2e-4)
#pragma unroll
  for (int i = 0; i < 16; ++i) {
    if (dr[i] >= thr) {
      const int pos = atomicAdd(&scount, 1);
      if (pos < 64) slist[pos] = i * 256 + tid;
    }
  }
  __syncthreads();

  if (tid < 64) {                             // wave 0: exact f64 re-rank of S
    const int s = min(scount, 64);
    int myi = -1; double myd = -1.0e300;
    if (tid < s) {
      myi = slist[tid];
      const float4 av = xb4[myi];
      const double c0 = (double)cx0, c1 = (double)cx1, c2 = (double)cx2;
      const double a0 = (double)av.x, a1 = (double)av.y, a2 = (double)av.z;
      const double dot = c0 * a0 + c1 * a1 + c2 * a2;
      const double sqm = a0 * a0 + a1 * a1 + a2 * a2;
      const double sn  = c0 * c0 + c1 * c1 + c2 * c2;
      myd = (2.0 * dot - sn) - sqm;
    }
    int rank = 0;
    for (int j = 0; j < s; ++j) {
      const double od = __shfl(myd, j);
      const int    oi = __shfl(myi, j);
      if (od > myd || (od == myd && oi < myi)) ++rank;
    }
    if (tid < s && rank < KNN) { idx_out[p * KNN + rank] = myi; eidx[rank] = myi; }
  }
  __syncthreads();

  // fused layer-1 stats: channel o = lane, k = (tid>>6) + 4t
  const int kb = tid >> 6;
  float sm = 0.f, sq = 0.f;
#pragma unroll
  for (int t = 0; t < 5; ++t) {
    const int kk = eidx[kb + 4 * t];
    const float4 qv = xb4[kk];                // same-addr broadcast in wave
    float y = w1r[0] * (qv.x - cx0) + w1r[1] * (qv.y - cx1) + w1r[2] * (qv.z - cx2) +
              w1r[3] * cx0 + w1r[4] * cx1 + w1r[5] * cx2;
    y = lrelu(y);
    sm += y; sq += y * y;
  }
  redS[tid] = sm; redQ[tid] = sq;
  __syncthreads();
  if (tid < 64) {
    const float s  = redS[tid] + redS[64 + tid] + redS[128 + tid] + redS[192 + tid];
    const float qq = redQ[tid] + redQ[64 + tid] + redQ[128 + tid] + redQ[192 + tid];
    float* bk = s1buf + (size_t)(p & 255) * 128;
    atomicAdd(&bk[tid], s);
    atomicAdd(&bk[64 + tid], qq);
  }
}

// ---------------------------------------------------------------------------
// Stage kernel (MFMA): one wave per point, 4 waves/block, 8 points/wave.
// Gather via packed xt4 (1 dwordx4/neighbor). MINW: stage2=3 (fits VGPR cap
// 170 spill-free), stage3=2 (needs w3f+acc3; proven at 2). See R5 for layout.
// ---------------------------------------------------------------------------
template <int STAGE, int MINW>
__global__ __launch_bounds__(256, MINW) void stage_kernel(
    const float4* __restrict__ xt4, const int* __restrict__ nbr,
    const float* __restrict__ W1,
    const float* __restrict__ w2ft, const float* __restrict__ b2f,
    const float* __restrict__ w3ft, const float* __restrict__ b3f,
    float* __restrict__ sumO, float* __restrict__ sqO,
    float* __restrict__ mx, float* __restrict__ mn) {
  __shared__ float pts[4][96];          // float4 per k, center at 80..83
  __shared__ float W1T[384];
  __shared__ short abuf[4][2048];       // per-wave A-frag buffer
  __shared__ float redS[256], redQ[256];

  const int tid = threadIdx.x, wave = tid >> 6, lane = tid & 63;
  const int q = lane >> 4, cc = lane & 15;

  for (int i = tid; i < 384; i += 256) W1T[i] = W1[(i & 63) * 6 + (i >> 6)];
  __syncthreads();

  float w1r[6];
#pragma unroll
  for (int c = 0; c < 6; ++c) w1r[c] = W1T[c * 64 + lane];

  bf16x8 w2f[2][4];
#pragma unroll
  for (int kt = 0; kt < 2; ++kt)
#pragma unroll
    for (int nt = 0; nt < 4; ++nt)
#pragma unroll
      for (int j = 0; j < 8; ++j)
        w2f[kt][nt][j] = f2bf(w2ft[(kt * 32 + q * 8 + j) * 64 + nt * 16 + cc]);
  float bias2v[4];
#pragma unroll
  for (int nt = 0; nt < 4; ++nt) bias2v[nt] = b2f[nt * 16 + cc];

  bf16x8 w3f[2][4];
  float bias3v[4];
  if (STAGE == 3) {
#pragma unroll
    for (int kt = 0; kt < 2; ++kt)
#pragma unroll
      for (int nt = 0; nt < 4; ++nt)
#pragma unroll
        for (int j = 0; j < 8; ++j)
          w3f[kt][nt][j] = f2bf(w3ft[(kt * 32 + q * 8 + j) * 64 + nt * 16 + cc]);
#pragma unroll
    for (int nt = 0; nt < 4; ++nt) bias3v[nt] = b3f[nt * 16 + cc];
  }

  const int kt1 = lane >> 5, q1 = (lane & 31) >> 3, j1 = lane & 7;
  short* ab = abuf[wave];
  const bf16x8* ab8 = (const bf16x8*)ab;
  float* pw = pts[wave];

  float s_s[4] = {0.f, 0.f, 0.f, 0.f}, s_q[4] = {0.f, 0.f, 0.f, 0.f};
  const int wgid = blockIdx.x * 4 + wave;

  for (int it = 0; it < 8; ++it) {
    const int p = wgid + it * 8192;
    const int b = p >> 12, n = p & 4095;
    const float4* xb4 = xt4 + (size_t)b * 4096;
    if (lane < KNN) {
      const int kk = nbr[p * KNN + lane];
      *(float4*)&pw[lane * 4] = xb4[kk];
    } else if (lane == KNN) {
      *(float4*)&pw[80] = xb4[n];
    }
    const float cx0 = pw[80], cx1 = pw[81], cx2 = pw[82];

#pragma unroll
    for (int k = 0; k < KNN; ++k) {
      const float4 pk = *(const float4*)&pw[k * 4];
      const float f0 = pk.x - cx0, f1 = pk.y - cx1, f2 = pk.z - cx2;
      float y = w1r[0] * f0 + w1r[1] * f1 + w1r[2] * f2 +
                w1r[3] * cx0 + w1r[4] * cx1 + w1r[5] * cx2;
      y = lrelu(y);
      ab[(((k >> 4) * 2 + kt1) * 64 + q1 * 16 + (k & 15)) * 8 + j1] = f2bf(y);
    }

    f32x4 acc2[2][4];
#pragma unroll
    for (int mt = 0; mt < 2; ++mt)
#pragma unroll
      for (int nt = 0; nt < 4; ++nt)
        acc2[mt][nt] = f32x4{bias2v[nt], bias2v[nt], bias2v[nt], bias2v[nt]};
#pragma unroll
    for (int kt = 0; kt < 2; ++kt) {
      const bf16x8 a0 = ab8[(0 * 2 + kt) * 64 + lane];
      const bf16x8 a1 = ab8[(1 * 2 + kt) * 64 + lane];
#pragma unroll
      for (int nt = 0; nt < 4; ++nt) {
        acc2[0][nt] = __builtin_amdgcn_mfma_f32_16x16x32_bf16(a0, w2f[kt][nt], acc2[0][nt], 0, 0, 0);
        acc2[1][nt] = __builtin_amdgcn_mfma_f32_16x16x32_bf16(a1, w2f[kt][nt], acc2[1][nt], 0, 0, 0);
      }
    }

    if (STAGE == 2) {
#pragma unroll
      for (int mt = 0; mt < 2; ++mt)
#pragma unroll
        for (int nt = 0; nt < 4; ++nt)
#pragma unroll
          for (int r = 0; r < 4; ++r) {
            if (mt == 1 && q != 0) continue;
            const float y = lrelu(acc2[mt][nt][r]);
            s_s[nt] += y; s_q[nt] += y * y;
          }
    } else {
#pragma unroll
      for (int mt = 0; mt < 2; ++mt)
#pragma unroll
        for (int nt = 0; nt < 4; ++nt) {
          const int kt3 = nt >> 1;
          const int q3 = (nt & 1) * 2 + (cc >> 3);
          const int j3 = cc & 7;
#pragma unroll
          for (int r = 0; r < 4; ++r) {
            if (mt == 1 && q != 0) continue;
            const float y = lrelu(acc2[mt][nt][r]);
            ab[((mt * 2 + kt3) * 64 + q3 * 16 + q * 4 + r) * 8 + j3] = f2bf(y);
          }
        }

      f32x4 acc3[2][4];
#pragma unroll
      for (int mt = 0; mt < 2; ++mt)
#pragma unroll
        for (int nt = 0; nt < 4; ++nt)
          acc3[mt][nt] = f32x4{bias3v[nt], bias3v[nt], bias3v[nt], bias3v[nt]};
#pragma unroll
      for (int kt = 0; kt < 2; ++kt) {
        const bf16x8 a0 = ab8[(0 * 2 + kt) * 64 + lane];
        const bf16x8 a1 = ab8[(1 * 2 + kt) * 64 + lane];
#pragma unroll
        for (int nt = 0; nt < 4; ++nt) {
          acc3[0][nt] = __builtin_amdgcn_mfma_f32_16x16x32_bf16(a0, w3f[kt][nt], acc3[0][nt], 0, 0, 0);
          acc3[1][nt] = __builtin_amdgcn_mfma_f32_16x16x32_bf16(a1, w3f[kt][nt], acc3[1][nt], 0, 0, 0);
        }
      }

      float vmx[4], vmn[4];
#pragma unroll
      for (int nt = 0; nt < 4; ++nt) { vmx[nt] = -INFINITY; vmn[nt] = INFINITY; }
#pragma unroll
      for (int mt = 0; mt < 2; ++mt)
#pragma unroll
        for (int nt = 0; nt < 4; ++nt)
#pragma unroll
          for (int r = 0; r < 4; ++r) {
            if (mt == 1 && q != 0) continue;
            const float y = lrelu(acc3[mt][nt][r]);
            s_s[nt] += y; s_q[nt] += y * y;
            vmx[nt] = fmaxf(vmx[nt], y); vmn[nt] = fminf(vmn[nt], y);
          }
#pragma unroll
      for (int nt = 0; nt < 4; ++nt) {
        vmx[nt] = fmaxf(vmx[nt], __shfl_xor(vmx[nt], 16));
        vmx[nt] = fmaxf(vmx[nt], __shfl_xor(vmx[nt], 32));
        vmn[nt] = fminf(vmn[nt], __shfl_xor(vmn[nt], 16));
        vmn[nt] = fminf(vmn[nt], __shfl_xor(vmn[nt], 32));
      }
      const float omx = q == 0 ? vmx[0] : q == 1 ? vmx[1] : q == 2 ? vmx[2] : vmx[3];
      const float omn = q == 0 ? vmn[0] : q == 1 ? vmn[1] : q == 2 ? vmn[2] : vmn[3];
      mx[(size_t)p * 64 + lane] = omx;
      mn[(size_t)p * 64 + lane] = omn;
    }
  }

#pragma unroll
  for (int nt = 0; nt < 4; ++nt) {
    s_s[nt] += __shfl_xor(s_s[nt], 16); s_s[nt] += __shfl_xor(s_s[nt], 32);
    s_q[nt] += __shfl_xor(s_q[nt], 16); s_q[nt] += __shfl_xor(s_q[nt], 32);
  }
  const float ms = q == 0 ? s_s[0] : q == 1 ? s_s[1] : q == 2 ? s_s[2] : s_s[3];
  const float mq = q == 0 ? s_q[0] : q == 1 ? s_q[1] : q == 2 ? s_q[2] : s_q[3];
  redS[tid] = ms; redQ[tid] = mq;
  __syncthreads();
  if (tid < 64) {
    const float s  = redS[tid] + redS[64 + tid] + redS[128 + tid] + redS[192 + tid];
    const float qq = redQ[tid] + redQ[64 + tid] + redQ[128 + tid] + redQ[192 + tid];
    atomicAdd(&sumO[tid], s);
    atomicAdd(&sqO[tid], qq);
  }
}

// fold1: sum 256 stat buckets, then fold BN into W2 (transposed + bias)
__global__ void fold1_kernel(const float* __restrict__ s1buf,
                             const float* __restrict__ g, const float* __restrict__ bt,
                             const float* __restrict__ W,
                             float* __restrict__ WfT, float* __restrict__ bf) {
  __shared__ float s[64], t[64];
  const int o = threadIdx.x;
  float sm = 0.f, qq = 0.f;
  for (int k = 0; k < 256; ++k) { sm += s1buf[k * 128 + o]; qq += s1buf[k * 128 + 64 + o]; }
  const float mu = sm * CNT_INV;
  const float var = qq * CNT_INV - mu * mu;
  const float sc = g[o] / sqrtf(var + 1e-5f);
  s[o] = sc; t[o] = bt[o] - mu * sc;
  __syncthreads();
  float acc = 0.f;
  for (int c = 0; c < 64; ++c) {
    const float w = W[o * 64 + c];
    WfT[c * 64 + o] = w * s[c];
    acc += w * t[c];
  }
  bf[o] = acc;
}

__global__ void fold_kernel(const float* __restrict__ sum, const float* __restrict__ sq,
                            const float* __restrict__ g, const float* __restrict__ bt,
                            const float* __restrict__ W,
                            float* __restrict__ WfT, float* __restrict__ bf) {
  __shared__ float s[64], t[64];
  const int o = threadIdx.x;
  const float mu = sum[o] * CNT_INV;
  const float var = sq[o] * CNT_INV - mu * mu;
  const float sc = g[o] / sqrtf(var + 1e-5f);
  s[o] = sc; t[o] = bt[o] - mu * sc;
  __syncthreads();
  float acc = 0.f;
  for (int c = 0; c < 64; ++c) {
    const float w = W[o * 64 + c];
    WfT[c * 64 + o] = w * s[c];
    acc += w * t[c];
  }
  bf[o] = acc;
}

__global__ void fold3_kernel(const float* __restrict__ sum, const float* __restrict__ sq,
                             const float* __restrict__ g, const float* __restrict__ bt,
                             float* __restrict__ s3, float* __restrict__ t3) {
  const int o = threadIdx.x;
  const float mu = sum[o] * CNT_INV;
  const float var = sq[o] * CNT_INV - mu * mu;
  const float sc = g[o] / sqrtf(var + 1e-5f);
  s3[o] = sc; t3[o] = bt[o] - mu * sc;
}

// final: 64x64 LDS transpose tile; coalesced reads of mx/mn AND writes of out.
// out[b][o][n] = s3[o] * (s3>=0 ? max_k : min_k) + t3[o]
__global__ __launch_bounds__(256) void final_kernel(
    const float* __restrict__ mx, const float* __restrict__ mn,
    const float* __restrict__ s3, const float* __restrict__ t3,
    float* __restrict__ out) {
  __shared__ float tmx[64][65], tmn[64][65];
  __shared__ float ss[64], tt[64];
  const int tid = threadIdx.x;
  const int P = blockIdx.x * 64;              // 64 points, same batch b
  const int b = P >> 12, nb = P & 4095;
  if (tid < 64) { ss[tid] = s3[tid]; tt[tid] = t3[tid]; }
#pragma unroll
  for (int r = 0; r < 16; ++r) {
    const int idx = r * 256 + tid;            // point-local row, channel
    const int pl = idx >> 6, ch = idx & 63;
    const size_t src = ((size_t)(P + pl)) * 64 + ch;
    tmx[pl][ch] = mx[src];
    tmn[pl][ch] = mn[src];
  }
  __syncthreads();
  const int nl = tid & 63;
#pragma unroll
  for (int r = 0; r < 16; ++r) {
    const int o = (tid >> 6) + r * 4;
    const float sc = ss[o];
    const float v = sc >= 0.f ? tmx[nl][o] : tmn[nl][o];
    out[(size_t)b * 262144 + (size_t)o * 4096 + nb + nl] = sc * v + tt[o];
  }
}

extern "C" void kernel_launch(void* const* d_in, const int* in_sizes, int n_in,
                              void* d_out, int out_size, void* d_ws, size_t ws_size,
                              hipStream_t stream) {
  const float* x  = (const float*)d_in[0];
  const float* W1 = (const float*)d_in[1];
  const float* W2 = (const float*)d_in[2];
  const float* W3 = (const float*)d_in[3];
  const float* g1 = (const float*)d_in[4];
  const float* b1 = (const float*)d_in[5];
  const float* g2 = (const float*)d_in[6];
  const float* b2 = (const float*)d_in[7];
  float* out = (float*)d_out;

  char* ws = (char*)d_ws;
  float4* xt4 = (float4*)ws;                        // 1,048,576 B
  int* idx = (int*)(ws + 1048576);                  // 5,242,880 B
  float* F = (float*)(ws + 6291456);
  float* sum2 = F + 0,   * sq2 = F + 64;
  float* sum3 = F + 128, * sq3 = F + 192;
  float* s1buf = F + 256;                           // 256 buckets x 128
  float* W2fT = F + 33024;
  float* b2f  = F + 37120;
  float* W3fT = F + 37184;
  float* b3f  = F + 41280;
  float* s3   = F + 41344;
  float* t3   = F + 41408;
  float* mx = (float*)(ws + 6457344);               // [B*N][64]
  float* mn = mx + (size_t)16 * 4096 * 64;

  hipMemsetAsync(F, 0, 33024 * sizeof(float), stream);   // stats + buckets

  xt4_kernel<<<256, 256, 0, stream>>>(x, xt4);
  knn_kernel<<<65536, 256, 0, stream>>>(xt4, idx, W1, s1buf);
  fold1_kernel<<<1, 64, 0, stream>>>(s1buf, g1, b1, W2, W2fT, b2f);
  stage_kernel<2, 3><<<2048, 256, 0, stream>>>(xt4, idx, W1, W2fT, b2f, nullptr,
                                               nullptr, sum2, sq2, nullptr, nullptr);
  fold_kernel<<<1, 64, 0, stream>>>(sum2, sq2, g1, b1, W3, W3fT, b3f);
  stage_kernel<3, 2><<<2048, 256, 0, stream>>>(xt4, idx, W1, W2fT, b2f, W3fT,
                                               b3f, sum3, sq3, mx, mn);
  fold3_kernel<<<1, 64, 0, stream>>>(sum3, sq3, g2, b2, s3, t3);
  final_kernel<<<1024, 256, 0, stream>>>(mx, mn, s3, t3, out);
}

// Round 10
// 688.850 us; speedup vs baseline: 1.2618x; 1.0081x over previous
//
#include <hip/hip_runtime.h>
#include <math.h>

#define KNN 20
#define CNT_INV (1.0f / 1310720.0f)   // 1 / (B*N*K)

typedef short bf16x8 __attribute__((ext_vector_type(8)));   // 8 bf16 in 4 VGPRs
typedef float f32x4  __attribute__((ext_vector_type(4)));

__device__ __forceinline__ short f2bf(float f) {            // RNE f32->bf16
  unsigned u = __builtin_bit_cast(unsigned, f);
  u += 0x7FFFu + ((u >> 16) & 1u);
  return (short)(u >> 16);
}
__device__ __forceinline__ float lrelu(float y) { return y > 0.f ? y : 0.2f * y; }

// pack xt4[b][m] = {x, y, z, |x|^2}
__global__ __launch_bounds__(256) void xt4_kernel(const float* __restrict__ x,
                                                  float4* __restrict__ xt4) {
  const int t = blockIdx.x * 256 + threadIdx.x;   // < 65536
  const int b = t >> 12, m = t & 4095;
  const float* xb = x + (size_t)b * 12288;
  const float a = xb[m], c = xb[4096 + m], e = xb[8192 + m];
  xt4[t] = make_float4(a, c, e, a * a + c * c + e * e);
}

// ---------------------------------------------------------------------------
// KNN dual-query + fused layer-1 BN stats. Block (256 thr) handles TWO query
// points: each candidate dwordx4 load feeds both dots (halves L2 traffic and
// barriers per query); f64 re-rank runs on waves 0/1 concurrently.
// Bisection on count(key>=T) via ballot+popcount; warm bracket [sqn-10, sqn];
// margin collect; exact f64 re-rank (reference op order) -> top-20 SET == np
// f64 top-k (downstream order-invariant).
// (R8 post-mortem: R8's failure was the stage kernels' launch_bounds(256,4)
//  resource-overrun launch failure, not this kernel — stages stay at R9's
//  proven (256,3)/(256,2) here.)
// ---------------------------------------------------------------------------
__global__ __launch_bounds__(256) void knn_kernel(const float4* __restrict__ xt4,
                                                  int* __restrict__ idx_out,
                                                  const float* __restrict__ W1,
                                                  float* __restrict__ s1buf) {
  __shared__ int wcnt[2][2][4];    // [phase][query][wave]
  __shared__ int slist[2][64];
  __shared__ int scnt[2];
  __shared__ int eidx[2][KNN];
  __shared__ float redS[2][128], redQ[2][128];
  const int tid = threadIdx.x, lane = tid & 63, wid = tid >> 6;
  const int p0 = blockIdx.x * 2;
  const int b = p0 >> 12, n0 = p0 & 4095;
  const float4* xb4 = xt4 + (size_t)b * 4096;
  const float4 cpa = xb4[n0], cpb = xb4[n0 + 1];

  float w1r[6];
#pragma unroll
  for (int c = 0; c < 6; ++c) w1r[c] = W1[lane * 6 + c];

  float dra[16], drb[16];
#pragma unroll
  for (int i = 0; i < 16; ++i) {
    const float4 qv = xb4[i * 256 + tid];
    const float da = fmaf(cpa.x, qv.x, fmaf(cpa.y, qv.y, cpa.z * qv.z));
    const float db = fmaf(cpb.x, qv.x, fmaf(cpb.y, qv.y, cpb.z * qv.z));
    dra[i] = fmaf(2.0f, da, -qv.w);           // key = 2*dot - sqm
    drb[i] = fmaf(2.0f, db, -qv.w);
  }

  int phase = 0;
  auto bcount2 = [&](float TA, float TB, int& CA, int& CB) {
    int c0 = 0, c1 = 0;
#pragma unroll
    for (int i = 0; i < 16; ++i) {
      c0 += (int)__popcll(__ballot(dra[i] >= TA));
      c1 += (int)__popcll(__ballot(drb[i] >= TB));
    }
    if (lane == 0) { wcnt[phase & 1][0][wid] = c0; wcnt[phase & 1][1][wid] = c1; }
    __syncthreads();
    const int (*wc)[4] = wcnt[phase & 1];
    CA = wc[0][0] + wc[0][1] + wc[0][2] + wc[0][3];
    CB = wc[1][0] + wc[1][1] + wc[1][2] + wc[1][3];
    ++phase;
  };

  float loa = cpa.w - 10.0f, hia = cpa.w + 1e-3f, Ta = loa;
  float lob = cpb.w - 10.0f, hib = cpb.w + 1e-3f, Tb = lob;
  int ca, cb;
  bcount2(Ta, Tb, ca, cb);
  if (ca < 20 || cb < 20) {                   // rare outlier: widen once
    if (ca < 20) { loa = cpa.w - 1e4f; Ta = loa; }
    if (cb < 20) { lob = cpb.w - 1e4f; Tb = lob; }
    bcount2(Ta, Tb, ca, cb);
  }
  bool da = (ca >= 20 && ca <= 48), db = (cb >= 20 && cb <= 48);
  for (int it = 0; it < 24 && !(da && db); ++it) {
    const float TA = da ? Ta : 0.5f * (loa + hia);
    const float TB = db ? Tb : 0.5f * (lob + hib);
    int nca, ncb;
    bcount2(TA, TB, nca, ncb);
    if (!da) {
      Ta = TA; ca = nca;
      if (ca < 20) hia = Ta; else if (ca > 48) loa = Ta; else da = true;
    }
    if (!db) {
      Tb = TB; cb = ncb;
      if (cb < 20) hib = Tb; else if (cb > 48) lob = Tb; else db = true;
    }
  }
  if (ca < 20) Ta = loa;                      // invariant: cnt(lo) >= 20
  if (cb < 20) Tb = lob;

  if (tid < 2) scnt[tid] = 0;
  __syncthreads();
  const float thra = Ta - 4e-3f, thrb = Tb - 4e-3f;  // margin >> f32 key err
#pragma unroll
  for (int i = 0; i < 16; ++i) {
    if (dra[i] >= thra) {
      const int pos = atomicAdd(&scnt[0], 1);
      if (pos < 64) slist[0][pos] = i * 256 + tid;
    }
    if (drb[i] >= thrb) {
      const int pos = atomicAdd(&scnt[1], 1);
      if (pos < 64) slist[1][pos] = i * 256 + tid;
    }
  }
  __syncthreads();

  if (wid < 2) {                              // waves 0/1: f64 re-rank q0/q1
    const int s = min(scnt[wid], 64);
    const float4 cp = wid ? cpb : cpa;
    int myi = -1; double myd = -1.0e300;
    if (lane < s) {
      myi = slist[wid][lane];
      const float4 av = xb4[myi];
      const double c0 = (double)cp.x, c1 = (double)cp.y, c2 = (double)cp.z;
      const double a0 = (double)av.x, a1 = (double)av.y, a2 = (double)av.z;
      const double dot = c0 * a0 + c1 * a1 + c2 * a2;
      const double sqm = a0 * a0 + a1 * a1 + a2 * a2;
      const double sn  = c0 * c0 + c1 * c1 + c2 * c2;
      myd = (2.0 * dot - sn) - sqm;
    }
    int rank = 0;
    for (int j = 0; j < s; ++j) {
      const double od = __shfl(myd, j);
      const int    oi = __shfl(myi, j);
      if (od > myd || (od == myd && oi < myi)) ++rank;
    }
    if (lane < s && rank < KNN) {
      idx_out[(p0 + wid) * KNN + rank] = myi;
      eidx[wid][rank] = myi;
    }
  }
  __syncthreads();

  // fused layer-1 stats: q = wid>>1 (2 waves/query), 10 k per wave, ch = lane
  const int q = wid >> 1, kb = wid & 1;
  const float4 cp = q ? cpb : cpa;
  float sm = 0.f, sq = 0.f;
#pragma unroll
  for (int t = 0; t < 10; ++t) {
    const int kk = eidx[q][kb * 10 + t];
    const float4 qv = xb4[kk];                // same-addr broadcast
    float y = w1r[0] * (qv.x - cp.x) + w1r[1] * (qv.y - cp.y) +
              w1r[2] * (qv.z - cp.z) +
              w1r[3] * cp.x + w1r[4] * cp.y + w1r[5] * cp.z;
    y = lrelu(y);
    sm += y; sq += y * y;
  }
  redS[q][kb * 64 + lane] = sm; redQ[q][kb * 64 + lane] = sq;
  __syncthreads();
  if (tid < 128) {
    const int q2 = tid >> 6, l2 = tid & 63;
    const float s  = redS[q2][l2] + redS[q2][64 + l2];
    const float qq = redQ[q2][l2] + redQ[q2][64 + l2];
    float* bk = s1buf + (size_t)((p0 + q2) & 255) * 128;
    atomicAdd(&bk[l2], s);
    atomicAdd(&bk[64 + l2], qq);
  }
}

// ---------------------------------------------------------------------------
// Stage kernel (MFMA): one wave per point, 4 waves/block, 8 points/wave.
// Gather via packed xt4 (1 dwordx4/neighbor). MINW: stage2=3, stage3=2
// (R8 lesson: (256,4) over-subscribes VGPRs -> launch failure). See R5.
// ---------------------------------------------------------------------------
template <int STAGE, int MINW>
__global__ __launch_bounds__(256, MINW) void stage_kernel(
    const float4* __restrict__ xt4, const int* __restrict__ nbr,
    const float* __restrict__ W1,
    const float* __restrict__ w2ft, const float* __restrict__ b2f,
    const float* __restrict__ w3ft, const float* __restrict__ b3f,
    float* __restrict__ sumO, float* __restrict__ sqO,
    float* __restrict__ mx, float* __restrict__ mn) {
  __shared__ float pts[4][96];          // float4 per k, center at 80..83
  __shared__ float W1T[384];
  __shared__ short abuf[4][2048];       // per-wave A-frag buffer
  __shared__ float redS[256], redQ[256];

  const int tid = threadIdx.x, wave = tid >> 6, lane = tid & 63;
  const int q = lane >> 4, cc = lane & 15;

  for (int i = tid; i < 384; i += 256) W1T[i] = W1[(i & 63) * 6 + (i >> 6)];
  __syncthreads();

  float w1r[6];
#pragma unroll
  for (int c = 0; c < 6; ++c) w1r[c] = W1T[c * 64 + lane];

  bf16x8 w2f[2][4];
#pragma unroll
  for (int kt = 0; kt < 2; ++kt)
#pragma unroll
    for (int nt = 0; nt < 4; ++nt)
#pragma unroll
      for (int j = 0; j < 8; ++j)
        w2f[kt][nt][j] = f2bf(w2ft[(kt * 32 + q * 8 + j) * 64 + nt * 16 + cc]);
  float bias2v[4];
#pragma unroll
  for (int nt = 0; nt < 4; ++nt) bias2v[nt] = b2f[nt * 16 + cc];

  bf16x8 w3f[2][4];
  float bias3v[4];
  if (STAGE == 3) {
#pragma unroll
    for (int kt = 0; kt < 2; ++kt)
#pragma unroll
      for (int nt = 0; nt < 4; ++nt)
#pragma unroll
        for (int j = 0; j < 8; ++j)
          w3f[kt][nt][j] = f2bf(w3ft[(kt * 32 + q * 8 + j) * 64 + nt * 16 + cc]);
#pragma unroll
    for (int nt = 0; nt < 4; ++nt) bias3v[nt] = b3f[nt * 16 + cc];
  }

  const int kt1 = lane >> 5, q1 = (lane & 31) >> 3, j1 = lane & 7;
  short* ab = abuf[wave];
  const bf16x8* ab8 = (const bf16x8*)ab;
  float* pw = pts[wave];

  float s_s[4] = {0.f, 0.f, 0.f, 0.f}, s_q[4] = {0.f, 0.f, 0.f, 0.f};
  const int wgid = blockIdx.x * 4 + wave;

  for (int it = 0; it < 8; ++it) {
    const int p = wgid + it * 8192;
    const int b = p >> 12, n = p & 4095;
    const float4* xb4 = xt4 + (size_t)b * 4096;
    if (lane < KNN) {
      const int kk = nbr[p * KNN + lane];
      *(float4*)&pw[lane * 4] = xb4[kk];
    } else if (lane == KNN) {
      *(float4*)&pw[80] = xb4[n];
    }
    const float cx0 = pw[80], cx1 = pw[81], cx2 = pw[82];

#pragma unroll
    for (int k = 0; k < KNN; ++k) {
      const float4 pk = *(const float4*)&pw[k * 4];
      const float f0 = pk.x - cx0, f1 = pk.y - cx1, f2 = pk.z - cx2;
      float y = w1r[0] * f0 + w1r[1] * f1 + w1r[2] * f2 +
                w1r[3] * cx0 + w1r[4] * cx1 + w1r[5] * cx2;
      y = lrelu(y);
      ab[(((k >> 4) * 2 + kt1) * 64 + q1 * 16 + (k & 15)) * 8 + j1] = f2bf(y);
    }

    f32x4 acc2[2][4];
#pragma unroll
    for (int mt = 0; mt < 2; ++mt)
#pragma unroll
      for (int nt = 0; nt < 4; ++nt)
        acc2[mt][nt] = f32x4{bias2v[nt], bias2v[nt], bias2v[nt], bias2v[nt]};
#pragma unroll
    for (int kt = 0; kt < 2; ++kt) {
      const bf16x8 a0 = ab8[(0 * 2 + kt) * 64 + lane];
      const bf16x8 a1 = ab8[(1 * 2 + kt) * 64 + lane];
#pragma unroll
      for (int nt = 0; nt < 4; ++nt) {
        acc2[0][nt] = __builtin_amdgcn_mfma_f32_16x16x32_bf16(a0, w2f[kt][nt], acc2[0][nt], 0, 0, 0);
        acc2[1][nt] = __builtin_amdgcn_mfma_f32_16x16x32_bf16(a1, w2f[kt][nt], acc2[1][nt], 0, 0, 0);
      }
    }

    if (STAGE == 2) {
#pragma unroll
      for (int mt = 0; mt < 2; ++mt)
#pragma unroll
        for (int nt = 0; nt < 4; ++nt)
#pragma unroll
          for (int r = 0; r < 4; ++r) {
            if (mt == 1 && q != 0) continue;
            const float y = lrelu(acc2[mt][nt][r]);
            s_s[nt] += y; s_q[nt] += y * y;
          }
    } else {
#pragma unroll
      for (int mt = 0; mt < 2; ++mt)
#pragma unroll
        for (int nt = 0; nt < 4; ++nt) {
          const int kt3 = nt >> 1;
          const int q3 = (nt & 1) * 2 + (cc >> 3);
          const int j3 = cc & 7;
#pragma unroll
          for (int r = 0; r < 4; ++r) {
            if (mt == 1 && q != 0) continue;
            const float y = lrelu(acc2[mt][nt][r]);
            ab[((mt * 2 + kt3) * 64 + q3 * 16 + q * 4 + r) * 8 + j3] = f2bf(y);
          }
        }

      f32x4 acc3[2][4];
#pragma unroll
      for (int mt = 0; mt < 2; ++mt)
#pragma unroll
        for (int nt = 0; nt < 4; ++nt)
          acc3[mt][nt] = f32x4{bias3v[nt], bias3v[nt], bias3v[nt], bias3v[nt]};
#pragma unroll
      for (int kt = 0; kt < 2; ++kt) {
        const bf16x8 a0 = ab8[(0 * 2 + kt) * 64 + lane];
        const bf16x8 a1 = ab8[(1 * 2 + kt) * 64 + lane];
#pragma unroll
        for (int nt = 0; nt < 4; ++nt) {
          acc3[0][nt] = __builtin_amdgcn_mfma_f32_16x16x32_bf16(a0, w3f[kt][nt], acc3[0][nt], 0, 0, 0);
          acc3[1][nt] = __builtin_amdgcn_mfma_f32_16x16x32_bf16(a1, w3f[kt][nt], acc3[1][nt], 0, 0, 0);
        }
      }

      float vmx[4], vmn[4];
#pragma unroll
      for (int nt = 0; nt < 4; ++nt) { vmx[nt] = -INFINITY; vmn[nt] = INFINITY; }
#pragma unroll
      for (int mt = 0; mt < 2; ++mt)
#pragma unroll
        for (int nt = 0; nt < 4; ++nt)
#pragma unroll
          for (int r = 0; r < 4; ++r) {
            if (mt == 1 && q != 0) continue;
            const float y = lrelu(acc3[mt][nt][r]);
            s_s[nt] += y; s_q[nt] += y * y;
            vmx[nt] = fmaxf(vmx[nt], y); vmn[nt] = fminf(vmn[nt], y);
          }
#pragma unroll
      for (int nt = 0; nt < 4; ++nt) {
        vmx[nt] = fmaxf(vmx[nt], __shfl_xor(vmx[nt], 16));
        vmx[nt] = fmaxf(vmx[nt], __shfl_xor(vmx[nt], 32));
        vmn[nt] = fminf(vmn[nt], __shfl_xor(vmn[nt], 16));
        vmn[nt] = fminf(vmn[nt], __shfl_xor(vmn[nt], 32));
      }
      const float omx = q == 0 ? vmx[0] : q == 1 ? vmx[1] : q == 2 ? vmx[2] : vmx[3];
      const float omn = q == 0 ? vmn[0] : q == 1 ? vmn[1] : q == 2 ? vmn[2] : vmn[3];
      mx[(size_t)p * 64 + lane] = omx;
      mn[(size_t)p * 64 + lane] = omn;
    }
  }

#pragma unroll
  for (int nt = 0; nt < 4; ++nt) {
    s_s[nt] += __shfl_xor(s_s[nt], 16); s_s[nt] += __shfl_xor(s_s[nt], 32);
    s_q[nt] += __shfl_xor(s_q[nt], 16); s_q[nt] += __shfl_xor(s_q[nt], 32);
  }
  const float ms = q == 0 ? s_s[0] : q == 1 ? s_s[1] : q == 2 ? s_s[2] : s_s[3];
  const float mq = q == 0 ? s_q[0] : q == 1 ? s_q[1] : q == 2 ? s_q[2] : s_q[3];
  redS[tid] = ms; redQ[tid] = mq;
  __syncthreads();
  if (tid < 64) {
    const float s  = redS[tid] + redS[64 + tid] + redS[128 + tid] + redS[192 + tid];
    const float qq = redQ[tid] + redQ[64 + tid] + redQ[128 + tid] + redQ[192 + tid];
    atomicAdd(&sumO[tid], s);
    atomicAdd(&sqO[tid], qq);
  }
}

// fold1: sum 256 stat buckets, then fold BN into W2 (transposed + bias)
__global__ void fold1_kernel(const float* __restrict__ s1buf,
                             const float* __restrict__ g, const float* __restrict__ bt,
                             const float* __restrict__ W,
                             float* __restrict__ WfT, float* __restrict__ bf) {
  __shared__ float s[64], t[64];
  const int o = threadIdx.x;
  float sm = 0.f, qq = 0.f;
  for (int k = 0; k < 256; ++k) { sm += s1buf[k * 128 + o]; qq += s1buf[k * 128 + 64 + o]; }
  const float mu = sm * CNT_INV;
  const float var = qq * CNT_INV - mu * mu;
  const float sc = g[o] / sqrtf(var + 1e-5f);
  s[o] = sc; t[o] = bt[o] - mu * sc;
  __syncthreads();
  float acc = 0.f;
  for (int c = 0; c < 64; ++c) {
    const float w = W[o * 64 + c];
    WfT[c * 64 + o] = w * s[c];
    acc += w * t[c];
  }
  bf[o] = acc;
}

__global__ void fold_kernel(const float* __restrict__ sum, const float* __restrict__ sq,
                            const float* __restrict__ g, const float* __restrict__ bt,
                            const float* __restrict__ W,
                            float* __restrict__ WfT, float* __restrict__ bf) {
  __shared__ float s[64], t[64];
  const int o = threadIdx.x;
  const float mu = sum[o] * CNT_INV;
  const float var = sq[o] * CNT_INV - mu * mu;
  const float sc = g[o] / sqrtf(var + 1e-5f);
  s[o] = sc; t[o] = bt[o] - mu * sc;
  __syncthreads();
  float acc = 0.f;
  for (int c = 0; c < 64; ++c) {
    const float w = W[o * 64 + c];
    WfT[c * 64 + o] = w * s[c];
    acc += w * t[c];
  }
  bf[o] = acc;
}

__global__ void fold3_kernel(const float* __restrict__ sum, const float* __restrict__ sq,
                             const float* __restrict__ g, const float* __restrict__ bt,
                             float* __restrict__ s3, float* __restrict__ t3) {
  const int o = threadIdx.x;
  const float mu = sum[o] * CNT_INV;
  const float var = sq[o] * CNT_INV - mu * mu;
  const float sc = g[o] / sqrtf(var + 1e-5f);
  s3[o] = sc; t3[o] = bt[o] - mu * sc;
}

// final: 64x64 LDS transpose tile; coalesced reads of mx/mn AND writes of out.
// out[b][o][n] = s3[o] * (s3>=0 ? max_k : min_k) + t3[o]
__global__ __launch_bounds__(256) void final_kernel(
    const float* __restrict__ mx, const float* __restrict__ mn,
    const float* __restrict__ s3, const float* __restrict__ t3,
    float* __restrict__ out) {
  __shared__ float tmx[64][65], tmn[64][65];
  __shared__ float ss[64], tt[64];
  const int tid = threadIdx.x;
  const int P = blockIdx.x * 64;              // 64 points, same batch b
  const int b = P >> 12, nb = P & 4095;
  if (tid < 64) { ss[tid] = s3[tid]; tt[tid] = t3[tid]; }
#pragma unroll
  for (int r = 0; r < 16; ++r) {
    const int idx = r * 256 + tid;            // point-local row, channel
    const int pl = idx >> 6, ch = idx & 63;
    const size_t src = ((size_t)(P + pl)) * 64 + ch;
    tmx[pl][ch] = mx[src];
    tmn[pl][ch] = mn[src];
  }
  __syncthreads();
  const int nl = tid & 63;
#pragma unroll
  for (int r = 0; r < 16; ++r) {
    const int o = (tid >> 6) + r * 4;
    const float sc = ss[o];
    const float v = sc >= 0.f ? tmx[nl][o] : tmn[nl][o];
    out[(size_t)b * 262144 + (size_t)o * 4096 + nb + nl] = sc * v + tt[o];
  }
}

extern "C" void kernel_launch(void* const* d_in, const int* in_sizes, int n_in,
                              void* d_out, int out_size, void* d_ws, size_t ws_size,
                              hipStream_t stream) {
  const float* x  = (const float*)d_in[0];
  const float* W1 = (const float*)d_in[1];
  const float* W2 = (const float*)d_in[2];
  const float* W3 = (const float*)d_in[3];
  const float* g1 = (const float*)d_in[4];
  const float* b1 = (const float*)d_in[5];
  const float* g2 = (const float*)d_in[6];
  const float* b2 = (const float*)d_in[7];
  float* out = (float*)d_out;

  char* ws = (char*)d_ws;
  float4* xt4 = (float4*)ws;                        // 1,048,576 B
  int* idx = (int*)(ws + 1048576);                  // 5,242,880 B
  float* F = (float*)(ws + 6291456);
  float* sum2 = F + 0,   * sq2 = F + 64;
  float* sum3 = F + 128, * sq3 = F + 192;
  float* s1buf = F + 256;                           // 256 buckets x 128
  float* W2fT = F + 33024;
  float* b2f  = F + 37120;
  float* W3fT = F + 37184;
  float* b3f  = F + 41280;
  float* s3   = F + 41344;
  float* t3   = F + 41408;
  float* mx = (float*)(ws + 6457344);               // [B*N][64]
  float* mn = mx + (size_t)16 * 4096 * 64;

  hipMemsetAsync(F, 0, 33024 * sizeof(float), stream);   // stats + buckets

  xt4_kernel<<<256, 256, 0, stream>>>(x, xt4);
  knn_kernel<<<32768, 256, 0, stream>>>(xt4, idx, W1, s1buf);
  fold1_kernel<<<1, 64, 0, stream>>>(s1buf, g1, b1, W2, W2fT, b2f);
  stage_kernel<2, 3><<<2048, 256, 0, stream>>>(xt4, idx, W1, W2fT, b2f, nullptr,
                                               nullptr, sum2, sq2, nullptr, nullptr);
  fold_kernel<<<1, 64, 0, stream>>>(sum2, sq2, g1, b1, W3, W3fT, b3f);
  stage_kernel<3, 2><<<2048, 256, 0, stream>>>(xt4, idx, W1, W2fT, b2f, W3fT,
                                               b3f, sum3, sq3, mx, mn);
  fold3_kernel<<<1, 64, 0, stream>>>(sum3, sq3, g2, b2, s3, t3);
  final_kernel<<<1024, 256, 0, stream>>>(mx, mn, s3, t3, out);
}

// Round 11
// 592.633 us; speedup vs baseline: 1.4667x; 1.1624x over previous
//
#include <hip/hip_runtime.h>
#include <math.h>

#define KNN 20
#define CNT_INV (1.0f / 1310720.0f)   // 1 / (B*N*K)

typedef short bf16x8 __attribute__((ext_vector_type(8)));   // 8 bf16 in 4 VGPRs
typedef float f32x4  __attribute__((ext_vector_type(4)));

__device__ __forceinline__ short f2bf(float f) {            // RNE f32->bf16
  unsigned u = __builtin_bit_cast(unsigned, f);
  u += 0x7FFFu + ((u >> 16) & 1u);
  return (short)(u >> 16);
}
__device__ __forceinline__ float lrelu(float y) { return y > 0.f ? y : 0.2f * y; }

// pack xt4[b][m] = {x, y, z, |x|^2}
__global__ __launch_bounds__(256) void xt4_kernel(const float* __restrict__ x,
                                                  float4* __restrict__ xt4) {
  const int t = blockIdx.x * 256 + threadIdx.x;   // < 65536
  const int b = t >> 12, m = t & 4095;
  const float* xb = x + (size_t)b * 12288;
  const float a = xb[m], c = xb[4096 + m], e = xb[8192 + m];
  xt4[t] = make_float4(a, c, e, a * a + c * c + e * e);
}

// ---------------------------------------------------------------------------
// KNN v7 (histogram select) + fused layer-1 BN stats. Block (256) per point.
// R10 lesson: bisection is ISSUE-bound (~12 rescans of 4096 keys). Replace
// with a one-pass 256-bin LDS histogram of d^2 over [lo, lo+R): per candidate
// 1 cmp (+ ~4 VALU + 1 DS atomic for the ~500 in-range), then one wave-0
// prefix scan finds first bin B with cumsum >= 20 -> Dedge = lo+(B+1)*bw.
// Rare block-uniform fallbacks: sparse (no bin reaches 20) -> R*=16;
// dense bin (cnt>48) -> zoom into bin B + direct recount of 'before'.
// Margin collect (d2 < Dedge+4e-3 covers f32-vs-f64 skew) -> exact f64
// re-rank of <=64 cands (reference op order) -> top-20 SET == np f64 top-k
// (downstream is order-invariant).
// ---------------------------------------------------------------------------
__global__ __launch_bounds__(256) void knn_kernel(const float4* __restrict__ xt4,
                                                  int* __restrict__ idx_out,
                                                  const float* __restrict__ W1,
                                                  float* __restrict__ s1buf) {
  __shared__ int hist[256];
  __shared__ int sB[2];
  __shared__ int wcnt[4];
  __shared__ int slist[64];
  __shared__ int scount;
  __shared__ int eidx[KNN];
  __shared__ float redS[256], redQ[256];
  const int p = blockIdx.x;
  const int b = p >> 12, n = p & 4095;
  const int tid = threadIdx.x, lane = tid & 63, wid = tid >> 6;
  const float4* xb4 = xt4 + (size_t)b * 4096;
  const float4 cp = xb4[n];                   // block-uniform
  const float cx0 = cp.x, cx1 = cp.y, cx2 = cp.z, sqn = cp.w;

  float w1r[6];
#pragma unroll
  for (int c = 0; c < 6; ++c) w1r[c] = W1[lane * 6 + c];

  float d2[16];
#pragma unroll
  for (int i = 0; i < 16; ++i) {
    const float4 qv = xb4[i * 256 + tid];
    const float dot = fmaf(cx0, qv.x, fmaf(cx1, qv.y, cx2 * qv.z));
    d2[i] = fmaxf(fmaf(-2.0f, dot, qv.w) + sqn, 0.0f);   // |x_n - x_m|^2 >= 0
  }

  // ---- adaptive histogram: find Dedge with 20 <= count(d2 < Dedge) <= 48 ----
  float lo = 0.0f, R = 1.0f;
  int before = 0;
  float Dedge = 1e30f;
  bool done = false;
  for (int pass = 0; pass < 6 && !done; ++pass) {
    hist[tid] = 0;
    __syncthreads();
    const float scale = 256.0f / R;
#pragma unroll
    for (int i = 0; i < 16; ++i) {
      const float rel = d2[i] - lo;
      if (rel >= 0.0f && rel < R) {
        int bin = (int)(rel * scale);
        bin = bin > 255 ? 255 : bin;
        atomicAdd(&hist[bin], 1);
      }
    }
    __syncthreads();
    if (tid < 64) {                 // wave 0: prefix scan + first-bin search
      int s0 = hist[lane], s1 = hist[64 + lane];
      int s2 = hist[128 + lane], s3 = hist[192 + lane];
#pragma unroll
      for (int off = 1; off < 64; off <<= 1) { const int t = __shfl_up(s0, off); if (lane >= off) s0 += t; }
#pragma unroll
      for (int off = 1; off < 64; off <<= 1) { const int t = __shfl_up(s1, off); if (lane >= off) s1 += t; }
#pragma unroll
      for (int off = 1; off < 64; off <<= 1) { const int t = __shfl_up(s2, off); if (lane >= off) s2 += t; }
#pragma unroll
      for (int off = 1; off < 64; off <<= 1) { const int t = __shfl_up(s3, off); if (lane >= off) s3 += t; }
      s1 += __shfl(s0, 63);
      s2 += __shfl(s1, 63);
      s3 += __shfl(s2, 63);
      s0 += before; s1 += before; s2 += before; s3 += before;
      int B = 256, cnt = 0;
      unsigned long long m = __ballot(s0 >= 20);          // uniform masks ->
      if (m) { const int l = __ffsll((long long)m) - 1; B = l; cnt = __shfl(s0, l); }
      else if ((m = __ballot(s1 >= 20)) != 0ull) { const int l = __ffsll((long long)m) - 1; B = 64 + l; cnt = __shfl(s1, l); }
      else if ((m = __ballot(s2 >= 20)) != 0ull) { const int l = __ffsll((long long)m) - 1; B = 128 + l; cnt = __shfl(s2, l); }
      else if ((m = __ballot(s3 >= 20)) != 0ull) { const int l = __ffsll((long long)m) - 1; B = 192 + l; cnt = __shfl(s3, l); }
      if (lane == 0) { sB[0] = B; sB[1] = cnt; }
    }
    __syncthreads();
    const int B = sB[0], cnt = sB[1];       // block-uniform decisions below
    if (B == 256) { R *= 16.0f; continue; } // sparse query: widen
    const float bw = R * (1.0f / 256.0f);
    Dedge = lo + (float)(B + 1) * bw;
    if (cnt <= 48) { done = true; break; }
    // dense bin: zoom into [lo + B*bw, lo + (B+1)*bw) and recount 'before'
    lo += (float)B * bw;
    R = bw;
    int c = 0;
#pragma unroll
    for (int i = 0; i < 16; ++i) c += (int)__popcll(__ballot(d2[i] < lo));
    if (lane == 0) wcnt[wid] = c;
    __syncthreads();
    before = wcnt[0] + wcnt[1] + wcnt[2] + wcnt[3];
    __syncthreads();
  }

  // ---- margin collect ----
  if (tid == 0) scount = 0;
  __syncthreads();
  const float Dthr = Dedge + 4e-3f;         // margin >> f32 d2 error (~1e-5)
#pragma unroll
  for (int i = 0; i < 16; ++i) {
    if (d2[i] < Dthr) {
      const int pos = atomicAdd(&scount, 1);
      if (pos < 64) slist[pos] = i * 256 + tid;
    }
  }
  __syncthreads();

  if (tid < 64) {                           // wave 0: exact f64 re-rank of S
    const int s = min(scount, 64);
    int myi = -1; double myd = -1.0e300;
    if (tid < s) {
      myi = slist[tid];
      const float4 av = xb4[myi];
      const double c0 = (double)cx0, c1 = (double)cx1, c2 = (double)cx2;
      const double a0 = (double)av.x, a1 = (double)av.y, a2 = (double)av.z;
      const double dot = c0 * a0 + c1 * a1 + c2 * a2;
      const double sqm = a0 * a0 + a1 * a1 + a2 * a2;
      const double sn  = c0 * c0 + c1 * c1 + c2 * c2;
      myd = (2.0 * dot - sn) - sqm;
    }
    int rank = 0;
    for (int j = 0; j < s; ++j) {
      const double od = __shfl(myd, j);
      const int    oi = __shfl(myi, j);
      if (od > myd || (od == myd && oi < myi)) ++rank;
    }
    if (tid < s && rank < KNN) { idx_out[p * KNN + rank] = myi; eidx[rank] = myi; }
  }
  __syncthreads();

  // fused layer-1 stats: channel o = lane, k = (tid>>6) + 4t
  const int kb = tid >> 6;
  float sm = 0.f, sq = 0.f;
#pragma unroll
  for (int t = 0; t < 5; ++t) {
    const int kk = eidx[kb + 4 * t];
    const float4 qv = xb4[kk];              // same-addr broadcast in wave
    float y = w1r[0] * (qv.x - cx0) + w1r[1] * (qv.y - cx1) + w1r[2] * (qv.z - cx2) +
              w1r[3] * cx0 + w1r[4] * cx1 + w1r[5] * cx2;
    y = lrelu(y);
    sm += y; sq += y * y;
  }
  redS[tid] = sm; redQ[tid] = sq;
  __syncthreads();
  if (tid < 64) {
    const float s  = redS[tid] + redS[64 + tid] + redS[128 + tid] + redS[192 + tid];
    const float qq = redQ[tid] + redQ[64 + tid] + redQ[128 + tid] + redQ[192 + tid];
    float* bk = s1buf + (size_t)(p & 255) * 128;
    atomicAdd(&bk[tid], s);
    atomicAdd(&bk[64 + tid], qq);
  }
}

// ---------------------------------------------------------------------------
// Stage kernel (MFMA): one wave per point, 4 waves/block, 8 points/wave.
// Gather via packed xt4 (1 dwordx4/neighbor). MINW: stage2=3, stage3=2
// (R8 lesson: (256,4) over-subscribes VGPRs -> launch failure). See R5.
// ---------------------------------------------------------------------------
template <int STAGE, int MINW>
__global__ __launch_bounds__(256, MINW) void stage_kernel(
    const float4* __restrict__ xt4, const int* __restrict__ nbr,
    const float* __restrict__ W1,
    const float* __restrict__ w2ft, const float* __restrict__ b2f,
    const float* __restrict__ w3ft, const float* __restrict__ b3f,
    float* __restrict__ sumO, float* __restrict__ sqO,
    float* __restrict__ mx, float* __restrict__ mn) {
  __shared__ float pts[4][96];          // float4 per k, center at 80..83
  __shared__ float W1T[384];
  __shared__ short abuf[4][2048];       // per-wave A-frag buffer
  __shared__ float redS[256], redQ[256];

  const int tid = threadIdx.x, wave = tid >> 6, lane = tid & 63;
  const int q = lane >> 4, cc = lane & 15;

  for (int i = tid; i < 384; i += 256) W1T[i] = W1[(i & 63) * 6 + (i >> 6)];
  __syncthreads();

  float w1r[6];
#pragma unroll
  for (int c = 0; c < 6; ++c) w1r[c] = W1T[c * 64 + lane];

  bf16x8 w2f[2][4];
#pragma unroll
  for (int kt = 0; kt < 2; ++kt)
#pragma unroll
    for (int nt = 0; nt < 4; ++nt)
#pragma unroll
      for (int j = 0; j < 8; ++j)
        w2f[kt][nt][j] = f2bf(w2ft[(kt * 32 + q * 8 + j) * 64 + nt * 16 + cc]);
  float bias2v[4];
#pragma unroll
  for (int nt = 0; nt < 4; ++nt) bias2v[nt] = b2f[nt * 16 + cc];

  bf16x8 w3f[2][4];
  float bias3v[4];
  if (STAGE == 3) {
#pragma unroll
    for (int kt = 0; kt < 2; ++kt)
#pragma unroll
      for (int nt = 0; nt < 4; ++nt)
#pragma unroll
        for (int j = 0; j < 8; ++j)
          w3f[kt][nt][j] = f2bf(w3ft[(kt * 32 + q * 8 + j) * 64 + nt * 16 + cc]);
#pragma unroll
    for (int nt = 0; nt < 4; ++nt) bias3v[nt] = b3f[nt * 16 + cc];
  }

  const int kt1 = lane >> 5, q1 = (lane & 31) >> 3, j1 = lane & 7;
  short* ab = abuf[wave];
  const bf16x8* ab8 = (const bf16x8*)ab;
  float* pw = pts[wave];

  float s_s[4] = {0.f, 0.f, 0.f, 0.f}, s_q[4] = {0.f, 0.f, 0.f, 0.f};
  const int wgid = blockIdx.x * 4 + wave;

  for (int it = 0; it < 8; ++it) {
    const int p = wgid + it * 8192;
    const int b = p >> 12, n = p & 4095;
    const float4* xb4 = xt4 + (size_t)b * 4096;
    if (lane < KNN) {
      const int kk = nbr[p * KNN + lane];
      *(float4*)&pw[lane * 4] = xb4[kk];
    } else if (lane == KNN) {
      *(float4*)&pw[80] = xb4[n];
    }
    const float cx0 = pw[80], cx1 = pw[81], cx2 = pw[82];

#pragma unroll
    for (int k = 0; k < KNN; ++k) {
      const float4 pk = *(const float4*)&pw[k * 4];
      const float f0 = pk.x - cx0, f1 = pk.y - cx1, f2 = pk.z - cx2;
      float y = w1r[0] * f0 + w1r[1] * f1 + w1r[2] * f2 +
                w1r[3] * cx0 + w1r[4] * cx1 + w1r[5] * cx2;
      y = lrelu(y);
      ab[(((k >> 4) * 2 + kt1) * 64 + q1 * 16 + (k & 15)) * 8 + j1] = f2bf(y);
    }

    f32x4 acc2[2][4];
#pragma unroll
    for (int mt = 0; mt < 2; ++mt)
#pragma unroll
      for (int nt = 0; nt < 4; ++nt)
        acc2[mt][nt] = f32x4{bias2v[nt], bias2v[nt], bias2v[nt], bias2v[nt]};
#pragma unroll
    for (int kt = 0; kt < 2; ++kt) {
      const bf16x8 a0 = ab8[(0 * 2 + kt) * 64 + lane];
      const bf16x8 a1 = ab8[(1 * 2 + kt) * 64 + lane];
#pragma unroll
      for (int nt = 0; nt < 4; ++nt) {
        acc2[0][nt] = __builtin_amdgcn_mfma_f32_16x16x32_bf16(a0, w2f[kt][nt], acc2[0][nt], 0, 0, 0);
        acc2[1][nt] = __builtin_amdgcn_mfma_f32_16x16x32_bf16(a1, w2f[kt][nt], acc2[1][nt], 0, 0, 0);
      }
    }

    if (STAGE == 2) {
#pragma unroll
      for (int mt = 0; mt < 2; ++mt)
#pragma unroll
        for (int nt = 0; nt < 4; ++nt)
#pragma unroll
          for (int r = 0; r < 4; ++r) {
            if (mt == 1 && q != 0) continue;
            const float y = lrelu(acc2[mt][nt][r]);
            s_s[nt] += y; s_q[nt] += y * y;
          }
    } else {
#pragma unroll
      for (int mt = 0; mt < 2; ++mt)
#pragma unroll
        for (int nt = 0; nt < 4; ++nt) {
          const int kt3 = nt >> 1;
          const int q3 = (nt & 1) * 2 + (cc >> 3);
          const int j3 = cc & 7;
#pragma unroll
          for (int r = 0; r < 4; ++r) {
            if (mt == 1 && q != 0) continue;
            const float y = lrelu(acc2[mt][nt][r]);
            ab[((mt * 2 + kt3) * 64 + q3 * 16 + q * 4 + r) * 8 + j3] = f2bf(y);
          }
        }

      f32x4 acc3[2][4];
#pragma unroll
      for (int mt = 0; mt < 2; ++mt)
#pragma unroll
        for (int nt = 0; nt < 4; ++nt)
          acc3[mt][nt] = f32x4{bias3v[nt], bias3v[nt], bias3v[nt], bias3v[nt]};
#pragma unroll
      for (int kt = 0; kt < 2; ++kt) {
        const bf16x8 a0 = ab8[(0 * 2 + kt) * 64 + lane];
        const bf16x8 a1 = ab8[(1 * 2 + kt) * 64 + lane];
#pragma unroll
        for (int nt = 0; nt < 4; ++nt) {
          acc3[0][nt] = __builtin_amdgcn_mfma_f32_16x16x32_bf16(a0, w3f[kt][nt], acc3[0][nt], 0, 0, 0);
          acc3[1][nt] = __builtin_amdgcn_mfma_f32_16x16x32_bf16(a1, w3f[kt][nt], acc3[1][nt], 0, 0, 0);
        }
      }

      float vmx[4], vmn[4];
#pragma unroll
      for (int nt = 0; nt < 4; ++nt) { vmx[nt] = -INFINITY; vmn[nt] = INFINITY; }
#pragma unroll
      for (int mt = 0; mt < 2; ++mt)
#pragma unroll
        for (int nt = 0; nt < 4; ++nt)
#pragma unroll
          for (int r = 0; r < 4; ++r) {
            if (mt == 1 && q != 0) continue;
            const float y = lrelu(acc3[mt][nt][r]);
            s_s[nt] += y; s_q[nt] += y * y;
            vmx[nt] = fmaxf(vmx[nt], y); vmn[nt] = fminf(vmn[nt], y);
          }
#pragma unroll
      for (int nt = 0; nt < 4; ++nt) {
        vmx[nt] = fmaxf(vmx[nt], __shfl_xor(vmx[nt], 16));
        vmx[nt] = fmaxf(vmx[nt], __shfl_xor(vmx[nt], 32));
        vmn[nt] = fminf(vmn[nt], __shfl_xor(vmn[nt], 16));
        vmn[nt] = fminf(vmn[nt], __shfl_xor(vmn[nt], 32));
      }
      const float omx = q == 0 ? vmx[0] : q == 1 ? vmx[1] : q == 2 ? vmx[2] : vmx[3];
      const float omn = q == 0 ? vmn[0] : q == 1 ? vmn[1] : q == 2 ? vmn[2] : vmn[3];
      mx[(size_t)p * 64 + lane] = omx;
      mn[(size_t)p * 64 + lane] = omn;
    }
  }

#pragma unroll
  for (int nt = 0; nt < 4; ++nt) {
    s_s[nt] += __shfl_xor(s_s[nt], 16); s_s[nt] += __shfl_xor(s_s[nt], 32);
    s_q[nt] += __shfl_xor(s_q[nt], 16); s_q[nt] += __shfl_xor(s_q[nt], 32);
  }
  const float ms = q == 0 ? s_s[0] : q == 1 ? s_s[1] : q == 2 ? s_s[2] : s_s[3];
  const float mq = q == 0 ? s_q[0] : q == 1 ? s_q[1] : q == 2 ? s_q[2] : s_q[3];
  redS[tid] = ms; redQ[tid] = mq;
  __syncthreads();
  if (tid < 64) {
    const float s  = redS[tid] + redS[64 + tid] + redS[128 + tid] + redS[192 + tid];
    const float qq = redQ[tid] + redQ[64 + tid] + redQ[128 + tid] + redQ[192 + tid];
    atomicAdd(&sumO[tid], s);
    atomicAdd(&sqO[tid], qq);
  }
}

// fold1: sum 256 stat buckets, then fold BN into W2 (transposed + bias)
__global__ void fold1_kernel(const float* __restrict__ s1buf,
                             const float* __restrict__ g, const float* __restrict__ bt,
                             const float* __restrict__ W,
                             float* __restrict__ WfT, float* __restrict__ bf) {
  __shared__ float s[64], t[64];
  const int o = threadIdx.x;
  float sm = 0.f, qq = 0.f;
  for (int k = 0; k < 256; ++k) { sm += s1buf[k * 128 + o]; qq += s1buf[k * 128 + 64 + o]; }
  const float mu = sm * CNT_INV;
  const float var = qq * CNT_INV - mu * mu;
  const float sc = g[o] / sqrtf(var + 1e-5f);
  s[o] = sc; t[o] = bt[o] - mu * sc;
  __syncthreads();
  float acc = 0.f;
  for (int c = 0; c < 64; ++c) {
    const float w = W[o * 64 + c];
    WfT[c * 64 + o] = w * s[c];
    acc += w * t[c];
  }
  bf[o] = acc;
}

__global__ void fold_kernel(const float* __restrict__ sum, const float* __restrict__ sq,
                            const float* __restrict__ g, const float* __restrict__ bt,
                            const float* __restrict__ W,
                            float* __restrict__ WfT, float* __restrict__ bf) {
  __shared__ float s[64], t[64];
  const int o = threadIdx.x;
  const float mu = sum[o] * CNT_INV;
  const float var = sq[o] * CNT_INV - mu * mu;
  const float sc = g[o] / sqrtf(var + 1e-5f);
  s[o] = sc; t[o] = bt[o] - mu * sc;
  __syncthreads();
  float acc = 0.f;
  for (int c = 0; c < 64; ++c) {
    const float w = W[o * 64 + c];
    WfT[c * 64 + o] = w * s[c];
    acc += w * t[c];
  }
  bf[o] = acc;
}

__global__ void fold3_kernel(const float* __restrict__ sum, const float* __restrict__ sq,
                             const float* __restrict__ g, const float* __restrict__ bt,
                             float* __restrict__ s3, float* __restrict__ t3) {
  const int o = threadIdx.x;
  const float mu = sum[o] * CNT_INV;
  const float var = sq[o] * CNT_INV - mu * mu;
  const float sc = g[o] / sqrtf(var + 1e-5f);
  s3[o] = sc; t3[o] = bt[o] - mu * sc;
}

// final: 64x64 LDS transpose tile; coalesced reads of mx/mn AND writes of out.
// out[b][o][n] = s3[o] * (s3>=0 ? max_k : min_k) + t3[o]
__global__ __launch_bounds__(256) void final_kernel(
    const float* __restrict__ mx, const float* __restrict__ mn,
    const float* __restrict__ s3, const float* __restrict__ t3,
    float* __restrict__ out) {
  __shared__ float tmx[64][65], tmn[64][65];
  __shared__ float ss[64], tt[64];
  const int tid = threadIdx.x;
  const int P = blockIdx.x * 64;              // 64 points, same batch b
  const int b = P >> 12, nb = P & 4095;
  if (tid < 64) { ss[tid] = s3[tid]; tt[tid] = t3[tid]; }
#pragma unroll
  for (int r = 0; r < 16; ++r) {
    const int idx = r * 256 + tid;            // point-local row, channel
    const int pl = idx >> 6, ch = idx & 63;
    const size_t src = ((size_t)(P + pl)) * 64 + ch;
    tmx[pl][ch] = mx[src];
    tmn[pl][ch] = mn[src];
  }
  __syncthreads();
  const int nl = tid & 63;
#pragma unroll
  for (int r = 0; r < 16; ++r) {
    const int o = (tid >> 6) + r * 4;
    const float sc = ss[o];
    const float v = sc >= 0.f ? tmx[nl][o] : tmn[nl][o];
    out[(size_t)b * 262144 + (size_t)o * 4096 + nb + nl] = sc * v + tt[o];
  }
}

extern "C" void kernel_launch(void* const* d_in, const int* in_sizes, int n_in,
                              void* d_out, int out_size, void* d_ws, size_t ws_size,
                              hipStream_t stream) {
  const float* x  = (const float*)d_in[0];
  const float* W1 = (const float*)d_in[1];
  const float* W2 = (const float*)d_in[2];
  const float* W3 = (const float*)d_in[3];
  const float* g1 = (const float*)d_in[4];
  const float* b1 = (const float*)d_in[5];
  const float* g2 = (const float*)d_in[6];
  const float* b2 = (const float*)d_in[7];
  float* out = (float*)d_out;

  char* ws = (char*)d_ws;
  float4* xt4 = (float4*)ws;                        // 1,048,576 B
  int* idx = (int*)(ws + 1048576);                  // 5,242,880 B
  float* F = (float*)(ws + 6291456);
  float* sum2 = F + 0,   * sq2 = F + 64;
  float* sum3 = F + 128, * sq3 = F + 192;
  float* s1buf = F + 256;                           // 256 buckets x 128
  float* W2fT = F + 33024;
  float* b2f  = F + 37120;
  float* W3fT = F + 37184;
  float* b3f  = F + 41280;
  float* s3   = F + 41344;
  float* t3   = F + 41408;
  float* mx = (float*)(ws + 6457344);               // [B*N][64]
  float* mn = mx + (size_t)16 * 4096 * 64;

  hipMemsetAsync(F, 0, 33024 * sizeof(float), stream);   // stats + buckets

  xt4_kernel<<<256, 256, 0, stream>>>(x, xt4);
  knn_kernel<<<65536, 256, 0, stream>>>(xt4, idx, W1, s1buf);
  fold1_kernel<<<1, 64, 0, stream>>>(s1buf, g1, b1, W2, W2fT, b2f);
  stage_kernel<2, 3><<<2048, 256, 0, stream>>>(xt4, idx, W1, W2fT, b2f, nullptr,
                                               nullptr, sum2, sq2, nullptr, nullptr);
  fold_kernel<<<1, 64, 0, stream>>>(sum2, sq2, g1, b1, W3, W3fT, b3f);
  stage_kernel<3, 2><<<2048, 256, 0, stream>>>(xt4, idx, W1, W2fT, b2f, W3fT,
                                               b3f, sum3, sq3, mx, mn);
  fold3_kernel<<<1, 64, 0, stream>>>(sum3, sq3, g2, b2, s3, t3);
  final_kernel<<<1024, 256, 0, stream>>>(mx, mn, s3, t3, out);
}

// Round 12
// 560.230 us; speedup vs baseline: 1.5515x; 1.0578x over previous
//
#include <hip/hip_runtime.h>
#include <math.h>

#define KNN 20
#define CNT_INV (1.0f / 1310720.0f)   // 1 / (B*N*K)

typedef short bf16x8 __attribute__((ext_vector_type(8)));   // 8 bf16 in 4 VGPRs
typedef float f32x4  __attribute__((ext_vector_type(4)));

__device__ __forceinline__ short f2bf(float f) {            // RNE f32->bf16
  unsigned u = __builtin_bit_cast(unsigned, f);
  u += 0x7FFFu + ((u >> 16) & 1u);
  return (short)(u >> 16);
}
__device__ __forceinline__ float lrelu(float y) { return y > 0.f ? y : 0.2f * y; }

// pack xt4[b][m] = {x, y, z, |x|^2}
__global__ __launch_bounds__(256) void xt4_kernel(const float* __restrict__ x,
                                                  float4* __restrict__ xt4) {
  const int t = blockIdx.x * 256 + threadIdx.x;   // < 65536
  const int b = t >> 12, m = t & 4095;
  const float* xb = x + (size_t)b * 12288;
  const float a = xb[m], c = xb[4096 + m], e = xb[8192 + m];
  xt4[t] = make_float4(a, c, e, a * a + c * c + e * e);
}

// ---------------------------------------------------------------------------
// KNN v8: dual-query histogram select + fused layer-1 BN stats.
// Block (256 thr) handles TWO queries: one shared candidate load feeds both
// d^2 computations (halves the 4.3 GB L2 candidate stream — R11's dominant
// remaining term). Selection per query: one-pass 256-bin LDS histogram of
// d^2 over [lo, lo+R) + wave-parallel prefix scan (wave w scans query w);
// rare block-uniform fallbacks (sparse -> R*=16; dense bin -> zoom+recount).
// Margin collect (d2 < Dedge+4e-3 covers f32-vs-f64 skew) -> exact f64
// re-rank (reference op order) on waves 0/1 -> top-20 SET == np f64 top-k
// (downstream is order-invariant). R10 proved the dual-query mechanics;
// R11 proved the histogram; this round composes them.
// ---------------------------------------------------------------------------
__global__ __launch_bounds__(256) void knn_kernel(const float4* __restrict__ xt4,
                                                  int* __restrict__ idx_out,
                                                  const float* __restrict__ W1,
                                                  float* __restrict__ s1buf) {
  __shared__ int hist[512];                 // [query][256]
  __shared__ int sB[4];                     // {B0,cnt0,B1,cnt1}
  __shared__ int wcnt[2][4];
  __shared__ int slist[2][64];
  __shared__ int scnt[2];
  __shared__ int eidx[2][KNN];
  __shared__ float redS[2][128], redQ[2][128];
  const int tid = threadIdx.x, lane = tid & 63, wid = tid >> 6;
  const int p0 = blockIdx.x * 2;
  const int b = p0 >> 12, n0 = p0 & 4095;
  const float4* xb4 = xt4 + (size_t)b * 4096;
  const float4 cpa = xb4[n0], cpb = xb4[n0 + 1];

  float w1r[6];
#pragma unroll
  for (int c = 0; c < 6; ++c) w1r[c] = W1[lane * 6 + c];

  float da[16], db[16];
#pragma unroll
  for (int i = 0; i < 16; ++i) {
    const float4 qv = xb4[i * 256 + tid];   // ONE load, two queries
    const float dta = fmaf(cpa.x, qv.x, fmaf(cpa.y, qv.y, cpa.z * qv.z));
    const float dtb = fmaf(cpb.x, qv.x, fmaf(cpb.y, qv.y, cpb.z * qv.z));
    da[i] = fmaxf(fmaf(-2.0f, dta, qv.w) + cpa.w, 0.0f);
    db[i] = fmaxf(fmaf(-2.0f, dtb, qv.w) + cpb.w, 0.0f);
  }

  // ---- adaptive dual histograms ----
  float lo0 = 0.f, R0 = 1.f, lo1 = 0.f, R1 = 1.f;
  int before0 = 0, before1 = 0;
  float Dedge0 = 1e30f, Dedge1 = 1e30f;
  bool done0 = false, done1 = false;
  for (int pass = 0; pass < 6 && !(done0 && done1); ++pass) {
    hist[tid] = 0; hist[256 + tid] = 0;
    __syncthreads();
    const float sc0 = 256.0f / R0, sc1 = 256.0f / R1;
#pragma unroll
    for (int i = 0; i < 16; ++i) {
      if (!done0) {
        const float rel = da[i] - lo0;
        if (rel >= 0.0f && rel < R0) {
          int bin = (int)(rel * sc0); bin = bin > 255 ? 255 : bin;
          atomicAdd(&hist[bin], 1);
        }
      }
      if (!done1) {
        const float rel = db[i] - lo1;
        if (rel >= 0.0f && rel < R1) {
          int bin = (int)(rel * sc1); bin = bin > 255 ? 255 : bin;
          atomicAdd(&hist[256 + bin], 1);
        }
      }
    }
    __syncthreads();
    if (wid < 2) {            // wave w: prefix scan of query w's histogram
      const bool skip = wid ? done1 : done0;
      if (!skip) {
        const int* h = &hist[wid * 256];
        int s0 = h[lane], s1 = h[64 + lane], s2 = h[128 + lane], s3 = h[192 + lane];
#pragma unroll
        for (int off = 1; off < 64; off <<= 1) { const int t = __shfl_up(s0, off); if (lane >= off) s0 += t; }
#pragma unroll
        for (int off = 1; off < 64; off <<= 1) { const int t = __shfl_up(s1, off); if (lane >= off) s1 += t; }
#pragma unroll
        for (int off = 1; off < 64; off <<= 1) { const int t = __shfl_up(s2, off); if (lane >= off) s2 += t; }
#pragma unroll
        for (int off = 1; off < 64; off <<= 1) { const int t = __shfl_up(s3, off); if (lane >= off) s3 += t; }
        s1 += __shfl(s0, 63);
        s2 += __shfl(s1, 63);
        s3 += __shfl(s2, 63);
        const int bef = wid ? before1 : before0;
        s0 += bef; s1 += bef; s2 += bef; s3 += bef;
        int B = 256, cnt = 0;
        unsigned long long m = __ballot(s0 >= 20);
        if (m) { const int l = __ffsll((long long)m) - 1; B = l; cnt = __shfl(s0, l); }
        else if ((m = __ballot(s1 >= 20)) != 0ull) { const int l = __ffsll((long long)m) - 1; B = 64 + l; cnt = __shfl(s1, l); }
        else if ((m = __ballot(s2 >= 20)) != 0ull) { const int l = __ffsll((long long)m) - 1; B = 128 + l; cnt = __shfl(s2, l); }
        else if ((m = __ballot(s3 >= 20)) != 0ull) { const int l = __ffsll((long long)m) - 1; B = 192 + l; cnt = __shfl(s3, l); }
        if (lane == 0) { sB[wid * 2] = B; sB[wid * 2 + 1] = cnt; }
      }
    }
    __syncthreads();
    // block-uniform per-query decisions
    bool zoom0 = false, zoom1 = false;
    if (!done0) {
      const int B = sB[0], cnt = sB[1];
      if (B == 256) R0 *= 16.0f;
      else {
        const float bw = R0 * (1.0f / 256.0f);
        Dedge0 = lo0 + (float)(B + 1) * bw;
        if (cnt <= 48) done0 = true;
        else { lo0 += (float)B * bw; R0 = bw; zoom0 = true; }
      }
    }
    if (!done1) {
      const int B = sB[2], cnt = sB[3];
      if (B == 256) R1 *= 16.0f;
      else {
        const float bw = R1 * (1.0f / 256.0f);
        Dedge1 = lo1 + (float)(B + 1) * bw;
        if (cnt <= 48) done1 = true;
        else { lo1 += (float)B * bw; R1 = bw; zoom1 = true; }
      }
    }
    if (zoom0) {
      int c = 0;
#pragma unroll
      for (int i = 0; i < 16; ++i) c += (int)__popcll(__ballot(da[i] < lo0));
      if (lane == 0) wcnt[0][wid] = c;
    }
    if (zoom1) {
      int c = 0;
#pragma unroll
      for (int i = 0; i < 16; ++i) c += (int)__popcll(__ballot(db[i] < lo1));
      if (lane == 0) wcnt[1][wid] = c;
    }
    if (zoom0 || zoom1) {
      __syncthreads();
      if (zoom0) before0 = wcnt[0][0] + wcnt[0][1] + wcnt[0][2] + wcnt[0][3];
      if (zoom1) before1 = wcnt[1][0] + wcnt[1][1] + wcnt[1][2] + wcnt[1][3];
    }
  }

  // ---- margin collect (both queries) ----
  if (tid < 2) scnt[tid] = 0;
  __syncthreads();
  const float Dthr0 = Dedge0 + 4e-3f, Dthr1 = Dedge1 + 4e-3f;
#pragma unroll
  for (int i = 0; i < 16; ++i) {
    if (da[i] < Dthr0) {
      const int pos = atomicAdd(&scnt[0], 1);
      if (pos < 64) slist[0][pos] = i * 256 + tid;
    }
    if (db[i] < Dthr1) {
      const int pos = atomicAdd(&scnt[1], 1);
      if (pos < 64) slist[1][pos] = i * 256 + tid;
    }
  }
  __syncthreads();

  if (wid < 2) {                              // waves 0/1: f64 re-rank q0/q1
    const int s = min(scnt[wid], 64);
    const float4 cp = wid ? cpb : cpa;
    int myi = -1; double myd = -1.0e300;
    if (lane < s) {
      myi = slist[wid][lane];
      const float4 av = xb4[myi];
      const double c0 = (double)cp.x, c1 = (double)cp.y, c2 = (double)cp.z;
      const double a0 = (double)av.x, a1 = (double)av.y, a2 = (double)av.z;
      const double dot = c0 * a0 + c1 * a1 + c2 * a2;
      const double sqm = a0 * a0 + a1 * a1 + a2 * a2;
      const double sn  = c0 * c0 + c1 * c1 + c2 * c2;
      myd = (2.0 * dot - sn) - sqm;
    }
    int rank = 0;
    for (int j = 0; j < s; ++j) {
      const double od = __shfl(myd, j);
      const int    oi = __shfl(myi, j);
      if (od > myd || (od == myd && oi < myi)) ++rank;
    }
    if (lane < s && rank < KNN) {
      idx_out[(p0 + wid) * KNN + rank] = myi;
      eidx[wid][rank] = myi;
    }
  }
  __syncthreads();

  // fused layer-1 stats: q = wid>>1 (2 waves/query), 10 k per wave, ch = lane
  const int q = wid >> 1, kb = wid & 1;
  const float4 cp = q ? cpb : cpa;
  float sm = 0.f, sq = 0.f;
#pragma unroll
  for (int t = 0; t < 10; ++t) {
    const int kk = eidx[q][kb * 10 + t];
    const float4 qv = xb4[kk];                // same-addr broadcast
    float y = w1r[0] * (qv.x - cp.x) + w1r[1] * (qv.y - cp.y) +
              w1r[2] * (qv.z - cp.z) +
              w1r[3] * cp.x + w1r[4] * cp.y + w1r[5] * cp.z;
    y = lrelu(y);
    sm += y; sq += y * y;
  }
  redS[q][kb * 64 + lane] = sm; redQ[q][kb * 64 + lane] = sq;
  __syncthreads();
  if (tid < 128) {
    const int q2 = tid >> 6, l2 = tid & 63;
    const float s  = redS[q2][l2] + redS[q2][64 + l2];
    const float qq = redQ[q2][l2] + redQ[q2][64 + l2];
    float* bk = s1buf + (size_t)((p0 + q2) & 255) * 128;
    atomicAdd(&bk[l2], s);
    atomicAdd(&bk[64 + l2], qq);
  }
}

// ---------------------------------------------------------------------------
// Stage kernel (MFMA): one wave per point, 4 waves/block, 8 points/wave.
// Gather via packed xt4 (1 dwordx4/neighbor). MINW: stage2=3, stage3=2
// (R8 lesson: (256,4) breaks — never again). See R5 for layout derivations.
// ---------------------------------------------------------------------------
template <int STAGE, int MINW>
__global__ __launch_bounds__(256, MINW) void stage_kernel(
    const float4* __restrict__ xt4, const int* __restrict__ nbr,
    const float* __restrict__ W1,
    const float* __restrict__ w2ft, const float* __restrict__ b2f,
    const float* __restrict__ w3ft, const float* __restrict__ b3f,
    float* __restrict__ sumO, float* __restrict__ sqO,
    float* __restrict__ mx, float* __restrict__ mn) {
  __shared__ float pts[4][96];          // float4 per k, center at 80..83
  __shared__ float W1T[384];
  __shared__ short abuf[4][2048];       // per-wave A-frag buffer
  __shared__ float redS[256], redQ[256];

  const int tid = threadIdx.x, wave = tid >> 6, lane = tid & 63;
  const int q = lane >> 4, cc = lane & 15;

  for (int i = tid; i < 384; i += 256) W1T[i] = W1[(i & 63) * 6 + (i >> 6)];
  __syncthreads();

  float w1r[6];
#pragma unroll
  for (int c = 0; c < 6; ++c) w1r[c] = W1T[c * 64 + lane];

  bf16x8 w2f[2][4];
#pragma unroll
  for (int kt = 0; kt < 2; ++kt)
#pragma unroll
    for (int nt = 0; nt < 4; ++nt)
#pragma unroll
      for (int j = 0; j < 8; ++j)
        w2f[kt][nt][j] = f2bf(w2ft[(kt * 32 + q * 8 + j) * 64 + nt * 16 + cc]);
  float bias2v[4];
#pragma unroll
  for (int nt = 0; nt < 4; ++nt) bias2v[nt] = b2f[nt * 16 + cc];

  bf16x8 w3f[2][4];
  float bias3v[4];
  if (STAGE == 3) {
#pragma unroll
    for (int kt = 0; kt < 2; ++kt)
#pragma unroll
      for (int nt = 0; nt < 4; ++nt)
#pragma unroll
        for (int j = 0; j < 8; ++j)
          w3f[kt][nt][j] = f2bf(w3ft[(kt * 32 + q * 8 + j) * 64 + nt * 16 + cc]);
#pragma unroll
    for (int nt = 0; nt < 4; ++nt) bias3v[nt] = b3f[nt * 16 + cc];
  }

  const int kt1 = lane >> 5, q1 = (lane & 31) >> 3, j1 = lane & 7;
  short* ab = abuf[wave];
  const bf16x8* ab8 = (const bf16x8*)ab;
  float* pw = pts[wave];

  float s_s[4] = {0.f, 0.f, 0.f, 0.f}, s_q[4] = {0.f, 0.f, 0.f, 0.f};
  const int wgid = blockIdx.x * 4 + wave;

  for (int it = 0; it < 8; ++it) {
    const int p = wgid + it * 8192;
    const int b = p >> 12, n = p & 4095;
    const float4* xb4 = xt4 + (size_t)b * 4096;
    if (lane < KNN) {
      const int kk = nbr[p * KNN + lane];
      *(float4*)&pw[lane * 4] = xb4[kk];
    } else if (lane == KNN) {
      *(float4*)&pw[80] = xb4[n];
    }
    const float cx0 = pw[80], cx1 = pw[81], cx2 = pw[82];

#pragma unroll
    for (int k = 0; k < KNN; ++k) {
      const float4 pk = *(const float4*)&pw[k * 4];
      const float f0 = pk.x - cx0, f1 = pk.y - cx1, f2 = pk.z - cx2;
      float y = w1r[0] * f0 + w1r[1] * f1 + w1r[2] * f2 +
                w1r[3] * cx0 + w1r[4] * cx1 + w1r[5] * cx2;
      y = lrelu(y);
      ab[(((k >> 4) * 2 + kt1) * 64 + q1 * 16 + (k & 15)) * 8 + j1] = f2bf(y);
    }

    f32x4 acc2[2][4];
#pragma unroll
    for (int mt = 0; mt < 2; ++mt)
#pragma unroll
      for (int nt = 0; nt < 4; ++nt)
        acc2[mt][nt] = f32x4{bias2v[nt], bias2v[nt], bias2v[nt], bias2v[nt]};
#pragma unroll
    for (int kt = 0; kt < 2; ++kt) {
      const bf16x8 a0 = ab8[(0 * 2 + kt) * 64 + lane];
      const bf16x8 a1 = ab8[(1 * 2 + kt) * 64 + lane];
#pragma unroll
      for (int nt = 0; nt < 4; ++nt) {
        acc2[0][nt] = __builtin_amdgcn_mfma_f32_16x16x32_bf16(a0, w2f[kt][nt], acc2[0][nt], 0, 0, 0);
        acc2[1][nt] = __builtin_amdgcn_mfma_f32_16x16x32_bf16(a1, w2f[kt][nt], acc2[1][nt], 0, 0, 0);
      }
    }

    if (STAGE == 2) {
#pragma unroll
      for (int mt = 0; mt < 2; ++mt)
#pragma unroll
        for (int nt = 0; nt < 4; ++nt)
#pragma unroll
          for (int r = 0; r < 4; ++r) {
            if (mt == 1 && q != 0) continue;
            const float y = lrelu(acc2[mt][nt][r]);
            s_s[nt] += y; s_q[nt] += y * y;
          }
    } else {
#pragma unroll
      for (int mt = 0; mt < 2; ++mt)
#pragma unroll
        for (int nt = 0; nt < 4; ++nt) {
          const int kt3 = nt >> 1;
          const int q3 = (nt & 1) * 2 + (cc >> 3);
          const int j3 = cc & 7;
#pragma unroll
          for (int r = 0; r < 4; ++r) {
            if (mt == 1 && q != 0) continue;
            const float y = lrelu(acc2[mt][nt][r]);
            ab[((mt * 2 + kt3) * 64 + q3 * 16 + q * 4 + r) * 8 + j3] = f2bf(y);
          }
        }

      f32x4 acc3[2][4];
#pragma unroll
      for (int mt = 0; mt < 2; ++mt)
#pragma unroll
        for (int nt = 0; nt < 4; ++nt)
          acc3[mt][nt] = f32x4{bias3v[nt], bias3v[nt], bias3v[nt], bias3v[nt]};
#pragma unroll
      for (int kt = 0; kt < 2; ++kt) {
        const bf16x8 a0 = ab8[(0 * 2 + kt) * 64 + lane];
        const bf16x8 a1 = ab8[(1 * 2 + kt) * 64 + lane];
#pragma unroll
        for (int nt = 0; nt < 4; ++nt) {
          acc3[0][nt] = __builtin_amdgcn_mfma_f32_16x16x32_bf16(a0, w3f[kt][nt], acc3[0][nt], 0, 0, 0);
          acc3[1][nt] = __builtin_amdgcn_mfma_f32_16x16x32_bf16(a1, w3f[kt][nt], acc3[1][nt], 0, 0, 0);
        }
      }

      float vmx[4], vmn[4];
#pragma unroll
      for (int nt = 0; nt < 4; ++nt) { vmx[nt] = -INFINITY; vmn[nt] = INFINITY; }
#pragma unroll
      for (int mt = 0; mt < 2; ++mt)
#pragma unroll
        for (int nt = 0; nt < 4; ++nt)
#pragma unroll
          for (int r = 0; r < 4; ++r) {
            if (mt == 1 && q != 0) continue;
            const float y = lrelu(acc3[mt][nt][r]);
            s_s[nt] += y; s_q[nt] += y * y;
            vmx[nt] = fmaxf(vmx[nt], y); vmn[nt] = fminf(vmn[nt], y);
          }
#pragma unroll
      for (int nt = 0; nt < 4; ++nt) {
        vmx[nt] = fmaxf(vmx[nt], __shfl_xor(vmx[nt], 16));
        vmx[nt] = fmaxf(vmx[nt], __shfl_xor(vmx[nt], 32));
        vmn[nt] = fminf(vmn[nt], __shfl_xor(vmn[nt], 16));
        vmn[nt] = fminf(vmn[nt], __shfl_xor(vmn[nt], 32));
      }
      const float omx = q == 0 ? vmx[0] : q == 1 ? vmx[1] : q == 2 ? vmx[2] : vmx[3];
      const float omn = q == 0 ? vmn[0] : q == 1 ? vmn[1] : q == 2 ? vmn[2] : vmn[3];
      mx[(size_t)p * 64 + lane] = omx;
      mn[(size_t)p * 64 + lane] = omn;
    }
  }

#pragma unroll
  for (int nt = 0; nt < 4; ++nt) {
    s_s[nt] += __shfl_xor(s_s[nt], 16); s_s[nt] += __shfl_xor(s_s[nt], 32);
    s_q[nt] += __shfl_xor(s_q[nt], 16); s_q[nt] += __shfl_xor(s_q[nt], 32);
  }
  const float ms = q == 0 ? s_s[0] : q == 1 ? s_s[1] : q == 2 ? s_s[2] : s_s[3];
  const float mq = q == 0 ? s_q[0] : q == 1 ? s_q[1] : q == 2 ? s_q[2] : s_q[3];
  redS[tid] = ms; redQ[tid] = mq;
  __syncthreads();
  if (tid < 64) {
    const float s  = redS[tid] + redS[64 + tid] + redS[128 + tid] + redS[192 + tid];
    const float qq = redQ[tid] + redQ[64 + tid] + redQ[128 + tid] + redQ[192 + tid];
    atomicAdd(&sumO[tid], s);
    atomicAdd(&sqO[tid], qq);
  }
}

// fold1: sum 256 stat buckets, then fold BN into W2 (transposed + bias)
__global__ void fold1_kernel(const float* __restrict__ s1buf,
                             const float* __restrict__ g, const float* __restrict__ bt,
                             const float* __restrict__ W,
                             float* __restrict__ WfT, float* __restrict__ bf) {
  __shared__ float s[64], t[64];
  const int o = threadIdx.x;
  float sm = 0.f, qq = 0.f;
  for (int k = 0; k < 256; ++k) { sm += s1buf[k * 128 + o]; qq += s1buf[k * 128 + 64 + o]; }
  const float mu = sm * CNT_INV;
  const float var = qq * CNT_INV - mu * mu;
  const float sc = g[o] / sqrtf(var + 1e-5f);
  s[o] = sc; t[o] = bt[o] - mu * sc;
  __syncthreads();
  float acc = 0.f;
  for (int c = 0; c < 64; ++c) {
    const float w = W[o * 64 + c];
    WfT[c * 64 + o] = w * s[c];
    acc += w * t[c];
  }
  bf[o] = acc;
}

__global__ void fold_kernel(const float* __restrict__ sum, const float* __restrict__ sq,
                            const float* __restrict__ g, const float* __restrict__ bt,
                            const float* __restrict__ W,
                            float* __restrict__ WfT, float* __restrict__ bf) {
  __shared__ float s[64], t[64];
  const int o = threadIdx.x;
  const float mu = sum[o] * CNT_INV;
  const float var = sq[o] * CNT_INV - mu * mu;
  const float sc = g[o] / sqrtf(var + 1e-5f);
  s[o] = sc; t[o] = bt[o] - mu * sc;
  __syncthreads();
  float acc = 0.f;
  for (int c = 0; c < 64; ++c) {
    const float w = W[o * 64 + c];
    WfT[c * 64 + o] = w * s[c];
    acc += w * t[c];
  }
  bf[o] = acc;
}

__global__ void fold3_kernel(const float* __restrict__ sum, const float* __restrict__ sq,
                             const float* __restrict__ g, const float* __restrict__ bt,
                             float* __restrict__ s3, float* __restrict__ t3) {
  const int o = threadIdx.x;
  const float mu = sum[o] * CNT_INV;
  const float var = sq[o] * CNT_INV - mu * mu;
  const float sc = g[o] / sqrtf(var + 1e-5f);
  s3[o] = sc; t3[o] = bt[o] - mu * sc;
}

// final: 64x64 LDS transpose tile; coalesced reads of mx/mn AND writes of out.
// out[b][o][n] = s3[o] * (s3>=0 ? max_k : min_k) + t3[o]
__global__ __launch_bounds__(256) void final_kernel(
    const float* __restrict__ mx, const float* __restrict__ mn,
    const float* __restrict__ s3, const float* __restrict__ t3,
    float* __restrict__ out) {
  __shared__ float tmx[64][65], tmn[64][65];
  __shared__ float ss[64], tt[64];
  const int tid = threadIdx.x;
  const int P = blockIdx.x * 64;              // 64 points, same batch b
  const int b = P >> 12, nb = P & 4095;
  if (tid < 64) { ss[tid] = s3[tid]; tt[tid] = t3[tid]; }
#pragma unroll
  for (int r = 0; r < 16; ++r) {
    const int idx = r * 256 + tid;            // point-local row, channel
    const int pl = idx >> 6, ch = idx & 63;
    const size_t src = ((size_t)(P + pl)) * 64 + ch;
    tmx[pl][ch] = mx[src];
    tmn[pl][ch] = mn[src];
  }
  __syncthreads();
  const int nl = tid & 63;
#pragma unroll
  for (int r = 0; r < 16; ++r) {
    const int o = (tid >> 6) + r * 4;
    const float sc = ss[o];
    const float v = sc >= 0.f ? tmx[nl][o] : tmn[nl][o];
    out[(size_t)b * 262144 + (size_t)o * 4096 + nb + nl] = sc * v + tt[o];
  }
}

extern "C" void kernel_launch(void* const* d_in, const int* in_sizes, int n_in,
                              void* d_out, int out_size, void* d_ws, size_t ws_size,
                              hipStream_t stream) {
  const float* x  = (const float*)d_in[0];
  const float* W1 = (const float*)d_in[1];
  const float* W2 = (const float*)d_in[2];
  const float* W3 = (const float*)d_in[3];
  const float* g1 = (const float*)d_in[4];
  const float* b1 = (const float*)d_in[5];
  const float* g2 = (const float*)d_in[6];
  const float* b2 = (const float*)d_in[7];
  float* out = (float*)d_out;

  char* ws = (char*)d_ws;
  float4* xt4 = (float4*)ws;                        // 1,048,576 B
  int* idx = (int*)(ws + 1048576);                  // 5,242,880 B
  float* F = (float*)(ws + 6291456);
  float* sum2 = F + 0,   * sq2 = F + 64;
  float* sum3 = F + 128, * sq3 = F + 192;
  float* s1buf = F + 256;                           // 256 buckets x 128
  float* W2fT = F + 33024;
  float* b2f  = F + 37120;
  float* W3fT = F + 37184;
  float* b3f  = F + 41280;
  float* s3   = F + 41344;
  float* t3   = F + 41408;
  float* mx = (float*)(ws + 6457344);               // [B*N][64]
  float* mn = mx + (size_t)16 * 4096 * 64;

  hipMemsetAsync(F, 0, 33024 * sizeof(float), stream);   // stats + buckets

  xt4_kernel<<<256, 256, 0, stream>>>(x, xt4);
  knn_kernel<<<32768, 256, 0, stream>>>(xt4, idx, W1, s1buf);
  fold1_kernel<<<1, 64, 0, stream>>>(s1buf, g1, b1, W2, W2fT, b2f);
  stage_kernel<2, 3><<<2048, 256, 0, stream>>>(xt4, idx, W1, W2fT, b2f, nullptr,
                                               nullptr, sum2, sq2, nullptr, nullptr);
  fold_kernel<<<1, 64, 0, stream>>>(sum2, sq2, g1, b1, W3, W3fT, b3f);
  stage_kernel<3, 2><<<2048, 256, 0, stream>>>(xt4, idx, W1, W2fT, b2f, W3fT,
                                               b3f, sum3, sq3, mx, mn);
  fold3_kernel<<<1, 64, 0, stream>>>(sum3, sq3, g2, b2, s3, t3);
  final_kernel<<<1024, 256, 0, stream>>>(mx, mn, s3, t3, out);
}